// Round 6
// baseline (426.259 us; speedup 1.0000x reference)
//
#include <hip/hip_runtime.h>
#include <hip/hip_bf16.h>

constexpr int NN   = 10000;
constexpr int NE   = 160000;
constexpr int INC  = 256;
constexpr int H    = 8;
constexpr int D1   = 1024;     // 8 heads x 128
constexpr int OUTC = 32;
constexpr int MPAD = 10112;    // 79 * 128
constexpr float NEG_SLOPE = 0.2f;

typedef __attribute__((ext_vector_type(8))) short bf16x8;
typedef __attribute__((ext_vector_type(4))) float f32x4;

__device__ __forceinline__ unsigned short f2b(float f) {
  unsigned u = __float_as_uint(f);
  unsigned r = (u + 0x7fffu + ((u >> 16) & 1u)) >> 16;
  return (unsigned short)r;
}
__device__ __forceinline__ float b2f_lo(unsigned u) { return __uint_as_float(u << 16); }
__device__ __forceinline__ float b2f_hi(unsigned u) { return __uint_as_float(u & 0xffff0000u); }
__device__ __forceinline__ float lrelu(float a) { return fmaxf(a, 0.f) + NEG_SLOPE * fminf(a, 0.f); }

// ---------------- CSR build ----------------
__global__ void deg_hist(const int* __restrict__ dst, int* __restrict__ deg) {
  int e = blockIdx.x * 256 + threadIdx.x;
  if (e < NE) atomicAdd(&deg[dst[e]], 1);
}
__global__ __launch_bounds__(64) void scan_rowptr(const int* __restrict__ deg,
                                                  int* __restrict__ rowptr,
                                                  int* __restrict__ cursor) {
  int lane = threadIdx.x;
  int carry = 0;
  for (int base = 0; base < NN; base += 64) {
    int i = base + lane;
    int v = (i < NN) ? deg[i] : 0;
    int s = v;
#pragma unroll
    for (int off = 1; off < 64; off <<= 1) {
      int t = __shfl_up(s, off);
      if (lane >= off) s += t;
    }
    if (i < NN) { rowptr[i] = carry + s - v; cursor[i] = carry + s - v; }
    carry += __shfl(s, 63);
  }
  if (lane == 0) rowptr[NN] = carry;
}
// sort edges by dst: csr_s[pos]=src, csr_d[pos]=dst (no csr_e indirection downstream)
__global__ void csr_fill(const int* __restrict__ src, const int* __restrict__ dst,
                         int* __restrict__ cursor,
                         int* __restrict__ csr_s, int* __restrict__ csr_d) {
  int e = blockIdx.x * 256 + threadIdx.x;
  if (e >= NE) return;
  int d = dst[e];
  int pos = atomicAdd(&cursor[d], 1);
  csr_s[pos] = src[e];
  csr_d[pos] = d;
}

// ---------------- conversions ----------------
__global__ void cvt_x(const float* __restrict__ x, short* __restrict__ Xb) {
  int i = blockIdx.x * 256 + threadIdx.x;
  int base = i * 4;
  if (base >= MPAD * INC) return;
  ushort4 o;
  if (base < NN * INC) {
    float4 v = *(const float4*)(x + base);
    o.x = f2b(v.x); o.y = f2b(v.y); o.z = f2b(v.z); o.w = f2b(v.w);
  } else {
    o.x = o.y = o.z = o.w = 0;
  }
  *(ushort4*)(Xb + base) = o;
}

// dual-source transpose+convert
__global__ __launch_bounds__(256) void transpose_cvt_dual(const float* __restrict__ srcA,
                                                          const float* __restrict__ srcB,
                                                          short* __restrict__ dst,
                                                          int K, int NsrcHalf) {
  __shared__ float tile[32][33];
  int tx = threadIdx.x & 31, ty = threadIdx.x >> 5;
  int nb = blockIdx.x * 32, kb = blockIdx.y * 32;
  const float* src = srcA;
  int nloc = nb;
  if (nb >= NsrcHalf) { src = srcB; nloc = nb - NsrcHalf; }
#pragma unroll
  for (int i = 0; i < 4; i++)
    tile[ty + i * 8][tx] = src[(size_t)(kb + ty + i * 8) * NsrcHalf + nloc + tx];
  __syncthreads();
#pragma unroll
  for (int i = 0; i < 4; i++)
    dst[(size_t)(nb + ty + i * 8) * K + kb + tx] = (short)f2b(tile[tx][ty + i * 8]);
}

// ---------------- bf16 MFMA GEMM ----------------
template<int BF16OUT>
__global__ __launch_bounds__(256) void gemm_bf16(const short* __restrict__ Xb,
                                                 const short* __restrict__ Wt,
                                                 void* __restrict__ Cout,
                                                 int M, int K, int ldc, int nvalid) {
  __shared__ short As[4096];
  __shared__ short Bs[4096];
  const int t = threadIdx.x;
  const int lane = t & 63;
  const int w = t >> 6;
  const int wr = w >> 1, wc = w & 1;
  const int row0 = blockIdx.y * 128;
  const int col0 = blockIdx.x * 128;
  const int r_st = t & 127;
  const int kc_st = t >> 7;
  f32x4 acc[4][4] = {};
  for (int k0 = 0; k0 < K; k0 += 32) {
    bf16x8 va0 = *(const bf16x8*)(Xb + (size_t)(row0 + r_st) * K + k0 + kc_st * 8);
    bf16x8 va1 = *(const bf16x8*)(Xb + (size_t)(row0 + r_st) * K + k0 + (kc_st + 2) * 8);
    bf16x8 vb0 = *(const bf16x8*)(Wt + (size_t)(col0 + r_st) * K + k0 + kc_st * 8);
    bf16x8 vb1 = *(const bf16x8*)(Wt + (size_t)(col0 + r_st) * K + k0 + (kc_st + 2) * 8);
    __syncthreads();
    *(bf16x8*)&As[(kc_st)     * 1024 + r_st * 8] = va0;
    *(bf16x8*)&As[(kc_st + 2) * 1024 + r_st * 8] = va1;
    *(bf16x8*)&Bs[(kc_st)     * 1024 + r_st * 8] = vb0;
    *(bf16x8*)&Bs[(kc_st + 2) * 1024 + r_st * 8] = vb1;
    __syncthreads();
    bf16x8 af[4], bfr[4];
#pragma unroll
    for (int i = 0; i < 4; i++)
      af[i] = *(const bf16x8*)&As[(lane >> 4) * 1024 + (wr * 64 + i * 16 + (lane & 15)) * 8];
#pragma unroll
    for (int j = 0; j < 4; j++)
      bfr[j] = *(const bf16x8*)&Bs[(lane >> 4) * 1024 + (wc * 64 + j * 16 + (lane & 15)) * 8];
#pragma unroll
    for (int i = 0; i < 4; i++)
#pragma unroll
      for (int j = 0; j < 4; j++)
        acc[i][j] = __builtin_amdgcn_mfma_f32_16x16x32_bf16(af[i], bfr[j], acc[i][j], 0, 0, 0);
  }
#pragma unroll
  for (int i = 0; i < 4; i++) {
    int rb = row0 + wr * 64 + i * 16 + (lane >> 4) * 4;
#pragma unroll
    for (int reg = 0; reg < 4; reg++) {
      int gr = rb + reg;
      if (gr < M) {
#pragma unroll
        for (int j = 0; j < 4; j++) {
          int gc = col0 + wc * 64 + j * 16 + (lane & 15);
          if (gc < nvalid) {
            if (BF16OUT) ((short*)Cout)[(size_t)gr * ldc + gc] = (short)f2b(acc[i][j][reg]);
            else         ((float*)Cout)[(size_t)gr * ldc + gc] = acc[i][j][reg];
          }
        }
      }
    }
  }
}

// ---------------- per-node att dot-products: alar[n][0..7]=att.xl, [8..15]=att.xr ----------------
__global__ __launch_bounds__(256) void prep_alar(const short* __restrict__ xlr,
                                                 const float* __restrict__ att,
                                                 float* __restrict__ alar) {
  const int n = blockIdx.x;
  const int t = threadIdx.x;
  const int ch = t * 8;
  const uint4 v = *(const uint4*)(xlr + (size_t)n * 2048 + ch);
  const int ac = ch & 1023;
  const float4 a0 = *(const float4*)(att + ac);
  const float4 a1 = *(const float4*)(att + ac + 4);
  float s = b2f_lo(v.x) * a0.x + b2f_hi(v.x) * a0.y
          + b2f_lo(v.y) * a0.z + b2f_hi(v.y) * a0.w
          + b2f_lo(v.z) * a1.x + b2f_hi(v.z) * a1.y
          + b2f_lo(v.w) * a1.z + b2f_hi(v.w) * a1.w;
#pragma unroll
  for (int off = 1; off < 16; off <<= 1) s += __shfl_xor(s, off);
  if ((t & 15) == 0) alar[n * 16 + (t >> 4)] = s;
}

// ---------------- layer-1 scores, CSR-ordered, wave per slot ----------------
// score = 0.6*(al[s,h]+ar[d,h]) + 0.4 * sum_c att[c]*|xl[s,c]+xr[d,c]|
// lane owns 16 channels (2x16B); 8-lane groups = one head; 3-level shfl reduce.
__global__ __launch_bounds__(256) void score1(const int* __restrict__ csr_s, const int* __restrict__ csr_d,
                                              const short* __restrict__ xlr, const float* __restrict__ att,
                                              const float* __restrict__ alar, float* __restrict__ sc1) {
  const int lane = threadIdx.x & 63;
  const int j = blockIdx.x * 4 + (threadIdx.x >> 6);
  if (j >= NE) return;
  const int s = csr_s[j], d = csr_d[j];
  const short* xls = xlr + (size_t)s * 2048 + lane * 16;
  const short* xrd = xlr + (size_t)d * 2048 + 1024 + lane * 16;
  uint4 la = *(const uint4*)xls;
  uint4 lb = *(const uint4*)(xls + 8);
  uint4 ra = *(const uint4*)xrd;
  uint4 rb = *(const uint4*)(xrd + 8);
  const float4* a4 = (const float4*)(att + lane * 16);
  float4 t0 = a4[0], t1 = a4[1], t2 = a4[2], t3 = a4[3];
  float p;
  p  = fabsf(b2f_lo(la.x) + b2f_lo(ra.x)) * t0.x;
  p += fabsf(b2f_hi(la.x) + b2f_hi(ra.x)) * t0.y;
  p += fabsf(b2f_lo(la.y) + b2f_lo(ra.y)) * t0.z;
  p += fabsf(b2f_hi(la.y) + b2f_hi(ra.y)) * t0.w;
  p += fabsf(b2f_lo(la.z) + b2f_lo(ra.z)) * t1.x;
  p += fabsf(b2f_hi(la.z) + b2f_hi(ra.z)) * t1.y;
  p += fabsf(b2f_lo(la.w) + b2f_lo(ra.w)) * t1.z;
  p += fabsf(b2f_hi(la.w) + b2f_hi(ra.w)) * t1.w;
  p += fabsf(b2f_lo(lb.x) + b2f_lo(rb.x)) * t2.x;
  p += fabsf(b2f_hi(lb.x) + b2f_hi(rb.x)) * t2.y;
  p += fabsf(b2f_lo(lb.y) + b2f_lo(rb.y)) * t2.z;
  p += fabsf(b2f_hi(lb.y) + b2f_hi(rb.y)) * t2.w;
  p += fabsf(b2f_lo(lb.z) + b2f_lo(rb.z)) * t3.x;
  p += fabsf(b2f_hi(lb.z) + b2f_hi(rb.z)) * t3.y;
  p += fabsf(b2f_lo(lb.w) + b2f_lo(rb.w)) * t3.z;
  p += fabsf(b2f_hi(lb.w) + b2f_hi(rb.w)) * t3.w;
#pragma unroll
  for (int off = 1; off < 8; off <<= 1) p += __shfl_xor(p, off);
  if ((lane & 7) == 0) {
    int h = lane >> 3;
    sc1[j * 8 + h] = 0.4f * p + 0.6f * (alar[s * 16 + h] + alar[d * 16 + 8 + h]);
  }
}

// ---------------- layer-1 segment softmax (thread per (dst,head)), linear reads ----------------
__global__ void softmax1(const int* __restrict__ rowptr, float* __restrict__ sc1) {
  int i = blockIdx.x * 256 + threadIdx.x;
  if (i >= NN * H) return;
  int d = i >> 3, h = i & 7;
  int jb = rowptr[d], je = rowptr[d + 1];
  if (jb == je) return;
  float m = -3.4e38f;
  for (int j = jb; j < je; j++) m = fmaxf(m, sc1[j * 8 + h]);
  float s = 0.f;
  for (int j = jb; j < je; j++) s += __expf(sc1[j * 8 + h] - m);
  float inv = 1.f / (s + 1e-16f);
  for (int j = jb; j < je; j++) sc1[j * 8 + h] = __expf(sc1[j * 8 + h] - m) * inv;
}

// ---------------- layer-1 aggregation: 2 waves per dst, wave-streaming, no barriers ----------------
// lane owns 8 channels (16B); alpha broadcast per 16-lane head group.
__global__ __launch_bounds__(256) void agg1_fast(const int* __restrict__ rowptr, const int* __restrict__ csr_s,
                                                 const float* __restrict__ alpha, const short* __restrict__ xlr,
                                                 const float* __restrict__ b1, short* __restrict__ h1b) {
  const int widx = threadIdx.x >> 6;
  const int lane = threadIdx.x & 63;
  const int d = blockIdx.x * 2 + (widx >> 1);
  const int ch = (widx & 1) * 512 + lane * 8;
  const int h = ch >> 7;
  const int jb = rowptr[d], je = rowptr[d + 1];
  float a0 = 0.f, a1 = 0.f, a2 = 0.f, a3 = 0.f, a4 = 0.f, a5 = 0.f, a6 = 0.f, a7 = 0.f;
#pragma unroll 2
  for (int j = jb; j < je; j++) {
    int s = csr_s[j];
    float al = alpha[j * 8 + h];
    uint4 v = *(const uint4*)(xlr + (size_t)s * 2048 + ch);
    a0 += al * b2f_lo(v.x); a1 += al * b2f_hi(v.x);
    a2 += al * b2f_lo(v.y); a3 += al * b2f_hi(v.y);
    a4 += al * b2f_lo(v.z); a5 += al * b2f_hi(v.z);
    a6 += al * b2f_lo(v.w); a7 += al * b2f_hi(v.w);
  }
  const float4 b0 = *(const float4*)(b1 + ch);
  const float4 b4 = *(const float4*)(b1 + ch + 4);
  a0 += b0.x; a1 += b0.y; a2 += b0.z; a3 += b0.w;
  a4 += b4.x; a5 += b4.y; a6 += b4.z; a7 += b4.w;
  a0 = a0 > 0.f ? a0 : expm1f(a0);
  a1 = a1 > 0.f ? a1 : expm1f(a1);
  a2 = a2 > 0.f ? a2 : expm1f(a2);
  a3 = a3 > 0.f ? a3 : expm1f(a3);
  a4 = a4 > 0.f ? a4 : expm1f(a4);
  a5 = a5 > 0.f ? a5 : expm1f(a5);
  a6 = a6 > 0.f ? a6 : expm1f(a6);
  a7 = a7 > 0.f ? a7 : expm1f(a7);
  ushort4 o0, o4;
  o0.x = f2b(a0); o0.y = f2b(a1); o0.z = f2b(a2); o0.w = f2b(a3);
  o4.x = f2b(a4); o4.y = f2b(a5); o4.z = f2b(a6); o4.w = f2b(a7);
  *(ushort4*)(h1b + (size_t)d * 1024 + ch) = o0;
  *(ushort4*)(h1b + (size_t)d * 1024 + ch + 4) = o4;
}

// ---------------- layer-2 scores, CSR-ordered (32 lanes per slot) ----------------
__global__ __launch_bounds__(256) void score2(const int* __restrict__ csr_s, const int* __restrict__ csr_d,
                                              const float* __restrict__ xlr2, const float* __restrict__ att2,
                                              float* __restrict__ sc2) {
  const int t = threadIdx.x;
  const int j = blockIdx.x * 8 + (t >> 5);
  const int c = t & 31;
  if (j >= NE) return;
  int s = csr_s[j], d = csr_d[j];
  float p = att2[c] * lrelu(xlr2[s * 64 + c] + xlr2[d * 64 + 32 + c]);
#pragma unroll
  for (int off = 16; off > 0; off >>= 1) p += __shfl_xor(p, off);
  if (c == 0) sc2[j] = p;
}

// ---------------- layer-2 segment softmax (thread per dst), linear ----------------
__global__ void softmax2(const int* __restrict__ rowptr, float* __restrict__ sc2) {
  int d = blockIdx.x * 256 + threadIdx.x;
  if (d >= NN) return;
  int jb = rowptr[d], je = rowptr[d + 1];
  if (jb == je) return;
  float m = -3.4e38f;
  for (int j = jb; j < je; j++) m = fmaxf(m, sc2[j]);
  float s = 0.f;
  for (int j = jb; j < je; j++) s += __expf(sc2[j] - m);
  float inv = 1.f / (s + 1e-16f);
  for (int j = jb; j < je; j++) sc2[j] = __expf(sc2[j] - m) * inv;
}

// ---------------- layer-2 aggregation + bias + log_softmax (32 lanes per dst) ----------------
__global__ __launch_bounds__(256) void agg2_fast(const int* __restrict__ rowptr, const int* __restrict__ csr_s,
                                                 const float* __restrict__ alpha2, const float* __restrict__ xlr2,
                                                 const float* __restrict__ b2, float* __restrict__ out) {
  const int t = threadIdx.x;
  const int d = blockIdx.x * 8 + (t >> 5);
  const int c = t & 31;
  if (d >= NN) return;
  const int jb = rowptr[d], je = rowptr[d + 1];
  float acc = 0.f;
#pragma unroll 2
  for (int j = jb; j < je; j++) {
    acc += alpha2[j] * xlr2[csr_s[j] * 64 + c];
  }
  float v = acc + b2[c];
  float mx = v;
#pragma unroll
  for (int off = 16; off > 0; off >>= 1) mx = fmaxf(mx, __shfl_xor(mx, off));
  float ex = __expf(v - mx);
  float sum = ex;
#pragma unroll
  for (int off = 16; off > 0; off >>= 1) sum += __shfl_xor(sum, off);
  out[d * 32 + c] = v - mx - logf(sum);
}

extern "C" void kernel_launch(void* const* d_in, const int* in_sizes, int n_in,
                              void* d_out, int out_size, void* d_ws, size_t ws_size,
                              hipStream_t stream) {
  const float* x    = (const float*)d_in[0];
  const int*   ei   = (const int*)d_in[1];
  const float* W1l  = (const float*)d_in[2];
  const float* W1r  = (const float*)d_in[3];
  const float* att1 = (const float*)d_in[4];
  const float* b1   = (const float*)d_in[5];
  const float* W2l  = (const float*)d_in[6];
  const float* W2r  = (const float*)d_in[7];
  const float* att2 = (const float*)d_in[8];
  const float* b2   = (const float*)d_in[9];
  float* out = (float*)d_out;

  // workspace layout
  short* Xb   = (short*)d_ws;                        // MPAD*256
  short* Wt1  = Xb + (size_t)MPAD * 256;             // 2048*256
  short* Wt2  = Wt1 + (size_t)2048 * 256;            // 128*1024
  short* xlr  = Wt2 + (size_t)128 * 1024;            // NN*2048 bf16 (xl | xr)
  short* h1b  = xlr + (size_t)NN * 2048;             // MPAD*1024 bf16
  float* xlr2 = (float*)(h1b + (size_t)MPAD * 1024); // NN*64
  float* alar = xlr2 + (size_t)NN * 64;              // NN*16
  float* sc1  = alar + (size_t)NN * 16;              // NE*8 (scores -> alphas)
  float* sc2  = sc1 + (size_t)NE * 8;                // NE
  int* deg    = (int*)(sc2 + NE);                    // NN
  int* rowptr = deg + NN;                            // NN+1
  int* cursor = rowptr + NN + 1;                     // NN
  int* csr_s  = cursor + NN;                         // NE
  int* csr_d  = csr_s + NE;                          // NE

  const int* src = ei;
  const int* dst = ei + NE;

  // CSR build (dst-sorted src/dst arrays)
  hipMemsetAsync(deg, 0, NN * sizeof(int), stream);
  deg_hist<<<(NE + 255) / 256, 256, 0, stream>>>(dst, deg);
  scan_rowptr<<<1, 64, 0, stream>>>(deg, rowptr, cursor);
  csr_fill<<<(NE + 255) / 256, 256, 0, stream>>>(src, dst, cursor, csr_s, csr_d);

  // conversions
  cvt_x<<<(MPAD * 256 / 4 + 255) / 256, 256, 0, stream>>>(x, Xb);
  {
    dim3 g(2048 / 32, 256 / 32);
    transpose_cvt_dual<<<g, 256, 0, stream>>>(W1l, W1r, Wt1, 256, 1024);
  }
  {
    dim3 g(64 / 32, 1024 / 32);
    transpose_cvt_dual<<<g, 256, 0, stream>>>(W2l, W2r, Wt2, 1024, 32);
    hipMemsetAsync(Wt2 + (size_t)64 * 1024, 0, (size_t)64 * 1024 * sizeof(short), stream);
  }

  // layer-1 GEMM -> xlr bf16 [NN][2048]
  {
    dim3 g(2048 / 128, MPAD / 128);
    gemm_bf16<1><<<g, 256, 0, stream>>>(Xb, Wt1, xlr, NN, 256, 2048, 2048);
  }

  // per-node att dots (separable 0.6u part of lrelu)
  prep_alar<<<NN, 256, 0, stream>>>(xlr, att1, alar);

  // layer-1 attention: flat phases
  score1<<<NE / 4, 256, 0, stream>>>(csr_s, csr_d, xlr, att1, alar, sc1);
  softmax1<<<(NN * H + 255) / 256, 256, 0, stream>>>(rowptr, sc1);
  agg1_fast<<<NN / 2, 256, 0, stream>>>(rowptr, csr_s, sc1, xlr, b1, h1b);

  // layer-2 GEMM -> xlr2 fp32 [NN][64]
  {
    dim3 g(1, MPAD / 128);
    gemm_bf16<0><<<g, 256, 0, stream>>>(h1b, Wt2, xlr2, NN, 1024, 64, 64);
  }

  // layer-2 attention: flat phases
  score2<<<NE / 8, 256, 0, stream>>>(csr_s, csr_d, xlr2, att2, sc2);
  softmax2<<<(NN + 255) / 256, 256, 0, stream>>>(rowptr, sc2);
  agg2_fast<<<(NN + 7) / 8, 256, 0, stream>>>(rowptr, csr_s, sc2, xlr2, b2, out);
}

// Round 7
// 359.657 us; speedup vs baseline: 1.1852x; 1.1852x over previous
//
#include <hip/hip_runtime.h>
#include <hip/hip_bf16.h>

constexpr int NN   = 10000;
constexpr int NE   = 160000;
constexpr int INC  = 256;
constexpr int H    = 8;
constexpr int D1   = 1024;     // 8 heads x 128
constexpr int OUTC = 32;
constexpr int MPAD = 10112;    // 79 * 128
constexpr float NEG_SLOPE = 0.2f;

typedef __attribute__((ext_vector_type(8))) short bf16x8;
typedef __attribute__((ext_vector_type(4))) float f32x4;

__device__ __forceinline__ unsigned short f2b(float f) {
  unsigned u = __float_as_uint(f);
  unsigned r = (u + 0x7fffu + ((u >> 16) & 1u)) >> 16;
  return (unsigned short)r;
}
__device__ __forceinline__ float b2f_lo(unsigned u) { return __uint_as_float(u << 16); }
__device__ __forceinline__ float b2f_hi(unsigned u) { return __uint_as_float(u & 0xffff0000u); }
__device__ __forceinline__ float lrelu(float a) { return fmaxf(a, 0.f) + NEG_SLOPE * fminf(a, 0.f); }

// ---------------- CSR build ----------------
__global__ void deg_hist(const int* __restrict__ dst, int* __restrict__ deg) {
  int e = blockIdx.x * 256 + threadIdx.x;
  if (e < NE) atomicAdd(&deg[dst[e]], 1);
}

// parallel exclusive scan: 1 block x 1024 threads, 10 elems/thread.
// thread-local serial scan -> wave shuffle-scan of totals -> LDS scan of 16
// wave totals -> add back. Writes rowptr[NN+1] and seeds cursor.
__global__ __launch_bounds__(1024) void scan_rowptr(const int* __restrict__ deg,
                                                    int* __restrict__ rowptr,
                                                    int* __restrict__ cursor) {
  __shared__ int wsum[16];
  const int t = threadIdx.x;
  const int lane = t & 63, w = t >> 6;
  const int base = t * 10;
  int v[10];
  int tot = 0;
#pragma unroll
  for (int i = 0; i < 10; i++) {
    int idx = base + i;
    int x = (idx < NN) ? deg[idx] : 0;
    v[i] = tot;            // exclusive prefix within thread
    tot += x;
  }
  int ws = tot;            // inclusive scan of thread totals within wave
#pragma unroll
  for (int off = 1; off < 64; off <<= 1) {
    int u = __shfl_up(ws, off);
    if (lane >= off) ws += u;
  }
  if (lane == 63) wsum[w] = ws;
  __syncthreads();
  if (w == 0) {
    int x = (lane < 16) ? wsum[lane] : 0;
#pragma unroll
    for (int off = 1; off < 16; off <<= 1) {
      int u = __shfl_up(x, off);
      if (lane >= off) x += u;
    }
    if (lane < 16) wsum[lane] = x;   // inclusive wave-total scan
  }
  __syncthreads();
  const int wbase = (w > 0) ? wsum[w - 1] : 0;
  const int tbase = wbase + ws - tot;
#pragma unroll
  for (int i = 0; i < 10; i++) {
    int idx = base + i;
    if (idx < NN) {
      int r = tbase + v[i];
      rowptr[idx] = r;
      cursor[idx] = r;
    }
  }
  if (t == 1023) rowptr[NN] = wbase + ws;   // grand total = NE
}

// sort edges by dst: csr_s[pos]=src, csr_d[pos]=dst
__global__ void csr_fill(const int* __restrict__ src, const int* __restrict__ dst,
                         int* __restrict__ cursor,
                         int* __restrict__ csr_s, int* __restrict__ csr_d) {
  int e = blockIdx.x * 256 + threadIdx.x;
  if (e >= NE) return;
  int d = dst[e];
  int pos = atomicAdd(&cursor[d], 1);
  csr_s[pos] = src[e];
  csr_d[pos] = d;
}

// ---------------- conversions ----------------
__global__ void cvt_x(const float* __restrict__ x, short* __restrict__ Xb) {
  int i = blockIdx.x * 256 + threadIdx.x;
  int base = i * 4;
  if (base >= MPAD * INC) return;
  ushort4 o;
  if (base < NN * INC) {
    float4 v = *(const float4*)(x + base);
    o.x = f2b(v.x); o.y = f2b(v.y); o.z = f2b(v.z); o.w = f2b(v.w);
  } else {
    o.x = o.y = o.z = o.w = 0;
  }
  *(ushort4*)(Xb + base) = o;
}

// dual-source transpose+convert
__global__ __launch_bounds__(256) void transpose_cvt_dual(const float* __restrict__ srcA,
                                                          const float* __restrict__ srcB,
                                                          short* __restrict__ dst,
                                                          int K, int NsrcHalf) {
  __shared__ float tile[32][33];
  int tx = threadIdx.x & 31, ty = threadIdx.x >> 5;
  int nb = blockIdx.x * 32, kb = blockIdx.y * 32;
  const float* src = srcA;
  int nloc = nb;
  if (nb >= NsrcHalf) { src = srcB; nloc = nb - NsrcHalf; }
#pragma unroll
  for (int i = 0; i < 4; i++)
    tile[ty + i * 8][tx] = src[(size_t)(kb + ty + i * 8) * NsrcHalf + nloc + tx];
  __syncthreads();
#pragma unroll
  for (int i = 0; i < 4; i++)
    dst[(size_t)(nb + ty + i * 8) * K + kb + tx] = (short)f2b(tile[tx][ty + i * 8]);
}

// ---------------- bf16 MFMA GEMM ----------------
template<int BF16OUT>
__global__ __launch_bounds__(256) void gemm_bf16(const short* __restrict__ Xb,
                                                 const short* __restrict__ Wt,
                                                 void* __restrict__ Cout,
                                                 int M, int K, int ldc, int nvalid) {
  __shared__ short As[4096];
  __shared__ short Bs[4096];
  const int t = threadIdx.x;
  const int lane = t & 63;
  const int w = t >> 6;
  const int wr = w >> 1, wc = w & 1;
  const int row0 = blockIdx.y * 128;
  const int col0 = blockIdx.x * 128;
  const int r_st = t & 127;
  const int kc_st = t >> 7;
  f32x4 acc[4][4] = {};
  for (int k0 = 0; k0 < K; k0 += 32) {
    bf16x8 va0 = *(const bf16x8*)(Xb + (size_t)(row0 + r_st) * K + k0 + kc_st * 8);
    bf16x8 va1 = *(const bf16x8*)(Xb + (size_t)(row0 + r_st) * K + k0 + (kc_st + 2) * 8);
    bf16x8 vb0 = *(const bf16x8*)(Wt + (size_t)(col0 + r_st) * K + k0 + kc_st * 8);
    bf16x8 vb1 = *(const bf16x8*)(Wt + (size_t)(col0 + r_st) * K + k0 + (kc_st + 2) * 8);
    __syncthreads();
    *(bf16x8*)&As[(kc_st)     * 1024 + r_st * 8] = va0;
    *(bf16x8*)&As[(kc_st + 2) * 1024 + r_st * 8] = va1;
    *(bf16x8*)&Bs[(kc_st)     * 1024 + r_st * 8] = vb0;
    *(bf16x8*)&Bs[(kc_st + 2) * 1024 + r_st * 8] = vb1;
    __syncthreads();
    bf16x8 af[4], bfr[4];
#pragma unroll
    for (int i = 0; i < 4; i++)
      af[i] = *(const bf16x8*)&As[(lane >> 4) * 1024 + (wr * 64 + i * 16 + (lane & 15)) * 8];
#pragma unroll
    for (int j = 0; j < 4; j++)
      bfr[j] = *(const bf16x8*)&Bs[(lane >> 4) * 1024 + (wc * 64 + j * 16 + (lane & 15)) * 8];
#pragma unroll
    for (int i = 0; i < 4; i++)
#pragma unroll
      for (int j = 0; j < 4; j++)
        acc[i][j] = __builtin_amdgcn_mfma_f32_16x16x32_bf16(af[i], bfr[j], acc[i][j], 0, 0, 0);
  }
#pragma unroll
  for (int i = 0; i < 4; i++) {
    int rb = row0 + wr * 64 + i * 16 + (lane >> 4) * 4;
#pragma unroll
    for (int reg = 0; reg < 4; reg++) {
      int gr = rb + reg;
      if (gr < M) {
#pragma unroll
        for (int j = 0; j < 4; j++) {
          int gc = col0 + wc * 64 + j * 16 + (lane & 15);
          if (gc < nvalid) {
            if (BF16OUT) ((short*)Cout)[(size_t)gr * ldc + gc] = (short)f2b(acc[i][j][reg]);
            else         ((float*)Cout)[(size_t)gr * ldc + gc] = acc[i][j][reg];
          }
        }
      }
    }
  }
}

// ---------------- per-node att dot-products: alar[n][0..7]=att.xl, [8..15]=att.xr ----------------
__global__ __launch_bounds__(256) void prep_alar(const short* __restrict__ xlr,
                                                 const float* __restrict__ att,
                                                 float* __restrict__ alar) {
  const int n = blockIdx.x;
  const int t = threadIdx.x;
  const int ch = t * 8;
  const uint4 v = *(const uint4*)(xlr + (size_t)n * 2048 + ch);
  const int ac = ch & 1023;
  const float4 a0 = *(const float4*)(att + ac);
  const float4 a1 = *(const float4*)(att + ac + 4);
  float s = b2f_lo(v.x) * a0.x + b2f_hi(v.x) * a0.y
          + b2f_lo(v.y) * a0.z + b2f_hi(v.y) * a0.w
          + b2f_lo(v.z) * a1.x + b2f_hi(v.z) * a1.y
          + b2f_lo(v.w) * a1.z + b2f_hi(v.w) * a1.w;
#pragma unroll
  for (int off = 1; off < 16; off <<= 1) s += __shfl_xor(s, off);
  if ((t & 15) == 0) alar[n * 16 + (t >> 4)] = s;
}

// ---------------- layer-1 scores, CSR-ordered, wave per slot ----------------
__global__ __launch_bounds__(256) void score1(const int* __restrict__ csr_s, const int* __restrict__ csr_d,
                                              const short* __restrict__ xlr, const float* __restrict__ att,
                                              const float* __restrict__ alar, float* __restrict__ sc1) {
  const int lane = threadIdx.x & 63;
  const int j = blockIdx.x * 4 + (threadIdx.x >> 6);
  if (j >= NE) return;
  const int s = csr_s[j], d = csr_d[j];
  const short* xls = xlr + (size_t)s * 2048 + lane * 16;
  const short* xrd = xlr + (size_t)d * 2048 + 1024 + lane * 16;
  uint4 la = *(const uint4*)xls;
  uint4 lb = *(const uint4*)(xls + 8);
  uint4 ra = *(const uint4*)xrd;
  uint4 rb = *(const uint4*)(xrd + 8);
  const float4* a4 = (const float4*)(att + lane * 16);
  float4 t0 = a4[0], t1 = a4[1], t2 = a4[2], t3 = a4[3];
  float p;
  p  = fabsf(b2f_lo(la.x) + b2f_lo(ra.x)) * t0.x;
  p += fabsf(b2f_hi(la.x) + b2f_hi(ra.x)) * t0.y;
  p += fabsf(b2f_lo(la.y) + b2f_lo(ra.y)) * t0.z;
  p += fabsf(b2f_hi(la.y) + b2f_hi(ra.y)) * t0.w;
  p += fabsf(b2f_lo(la.z) + b2f_lo(ra.z)) * t1.x;
  p += fabsf(b2f_hi(la.z) + b2f_hi(ra.z)) * t1.y;
  p += fabsf(b2f_lo(la.w) + b2f_lo(ra.w)) * t1.z;
  p += fabsf(b2f_hi(la.w) + b2f_hi(ra.w)) * t1.w;
  p += fabsf(b2f_lo(lb.x) + b2f_lo(rb.x)) * t2.x;
  p += fabsf(b2f_hi(lb.x) + b2f_hi(rb.x)) * t2.y;
  p += fabsf(b2f_lo(lb.y) + b2f_lo(rb.y)) * t2.z;
  p += fabsf(b2f_hi(lb.y) + b2f_hi(rb.y)) * t2.w;
  p += fabsf(b2f_lo(lb.z) + b2f_lo(rb.z)) * t3.x;
  p += fabsf(b2f_hi(lb.z) + b2f_hi(rb.z)) * t3.y;
  p += fabsf(b2f_lo(lb.w) + b2f_lo(rb.w)) * t3.z;
  p += fabsf(b2f_hi(lb.w) + b2f_hi(rb.w)) * t3.w;
#pragma unroll
  for (int off = 1; off < 8; off <<= 1) p += __shfl_xor(p, off);
  if ((lane & 7) == 0) {
    int h = lane >> 3;
    sc1[j * 8 + h] = 0.4f * p + 0.6f * (alar[s * 16 + h] + alar[d * 16 + 8 + h]);
  }
}

// ---------------- layer-1 segment softmax (thread per (dst,head)) ----------------
__global__ void softmax1(const int* __restrict__ rowptr, float* __restrict__ sc1) {
  int i = blockIdx.x * 256 + threadIdx.x;
  if (i >= NN * H) return;
  int d = i >> 3, h = i & 7;
  int jb = rowptr[d], je = rowptr[d + 1];
  if (jb == je) return;
  float m = -3.4e38f;
  for (int j = jb; j < je; j++) m = fmaxf(m, sc1[j * 8 + h]);
  float s = 0.f;
  for (int j = jb; j < je; j++) s += __expf(sc1[j * 8 + h] - m);
  float inv = 1.f / (s + 1e-16f);
  for (int j = jb; j < je; j++) sc1[j * 8 + h] = __expf(sc1[j * 8 + h] - m) * inv;
}

// ---------------- layer-1 aggregation: 2 waves per dst, wave-streaming ----------------
__global__ __launch_bounds__(256) void agg1_fast(const int* __restrict__ rowptr, const int* __restrict__ csr_s,
                                                 const float* __restrict__ alpha, const short* __restrict__ xlr,
                                                 const float* __restrict__ b1, short* __restrict__ h1b) {
  const int widx = threadIdx.x >> 6;
  const int lane = threadIdx.x & 63;
  const int d = blockIdx.x * 2 + (widx >> 1);
  const int ch = (widx & 1) * 512 + lane * 8;
  const int h = ch >> 7;
  const int jb = rowptr[d], je = rowptr[d + 1];
  float a0 = 0.f, a1 = 0.f, a2 = 0.f, a3 = 0.f, a4 = 0.f, a5 = 0.f, a6 = 0.f, a7 = 0.f;
#pragma unroll 4
  for (int j = jb; j < je; j++) {
    int s = csr_s[j];
    float al = alpha[j * 8 + h];
    uint4 v = *(const uint4*)(xlr + (size_t)s * 2048 + ch);
    a0 += al * b2f_lo(v.x); a1 += al * b2f_hi(v.x);
    a2 += al * b2f_lo(v.y); a3 += al * b2f_hi(v.y);
    a4 += al * b2f_lo(v.z); a5 += al * b2f_hi(v.z);
    a6 += al * b2f_lo(v.w); a7 += al * b2f_hi(v.w);
  }
  const float4 b0 = *(const float4*)(b1 + ch);
  const float4 b4 = *(const float4*)(b1 + ch + 4);
  a0 += b0.x; a1 += b0.y; a2 += b0.z; a3 += b0.w;
  a4 += b4.x; a5 += b4.y; a6 += b4.z; a7 += b4.w;
  a0 = a0 > 0.f ? a0 : expm1f(a0);
  a1 = a1 > 0.f ? a1 : expm1f(a1);
  a2 = a2 > 0.f ? a2 : expm1f(a2);
  a3 = a3 > 0.f ? a3 : expm1f(a3);
  a4 = a4 > 0.f ? a4 : expm1f(a4);
  a5 = a5 > 0.f ? a5 : expm1f(a5);
  a6 = a6 > 0.f ? a6 : expm1f(a6);
  a7 = a7 > 0.f ? a7 : expm1f(a7);
  ushort4 o0, o4;
  o0.x = f2b(a0); o0.y = f2b(a1); o0.z = f2b(a2); o0.w = f2b(a3);
  o4.x = f2b(a4); o4.y = f2b(a5); o4.z = f2b(a6); o4.w = f2b(a7);
  *(ushort4*)(h1b + (size_t)d * 1024 + ch) = o0;
  *(ushort4*)(h1b + (size_t)d * 1024 + ch + 4) = o4;
}

// ---------------- layer-2 scores, CSR-ordered (32 lanes per slot) ----------------
__global__ __launch_bounds__(256) void score2(const int* __restrict__ csr_s, const int* __restrict__ csr_d,
                                              const float* __restrict__ xlr2, const float* __restrict__ att2,
                                              float* __restrict__ sc2) {
  const int t = threadIdx.x;
  const int j = blockIdx.x * 8 + (t >> 5);
  const int c = t & 31;
  if (j >= NE) return;
  int s = csr_s[j], d = csr_d[j];
  float p = att2[c] * lrelu(xlr2[s * 64 + c] + xlr2[d * 64 + 32 + c]);
#pragma unroll
  for (int off = 16; off > 0; off >>= 1) p += __shfl_xor(p, off);
  if (c == 0) sc2[j] = p;
}

// ---------------- layer-2 segment softmax (thread per dst) ----------------
__global__ void softmax2(const int* __restrict__ rowptr, float* __restrict__ sc2) {
  int d = blockIdx.x * 256 + threadIdx.x;
  if (d >= NN) return;
  int jb = rowptr[d], je = rowptr[d + 1];
  if (jb == je) return;
  float m = -3.4e38f;
  for (int j = jb; j < je; j++) m = fmaxf(m, sc2[j]);
  float s = 0.f;
  for (int j = jb; j < je; j++) s += __expf(sc2[j] - m);
  float inv = 1.f / (s + 1e-16f);
  for (int j = jb; j < je; j++) sc2[j] = __expf(sc2[j] - m) * inv;
}

// ---------------- layer-2 aggregation + bias + log_softmax (32 lanes per dst) ----------------
__global__ __launch_bounds__(256) void agg2_fast(const int* __restrict__ rowptr, const int* __restrict__ csr_s,
                                                 const float* __restrict__ alpha2, const float* __restrict__ xlr2,
                                                 const float* __restrict__ b2, float* __restrict__ out) {
  const int t = threadIdx.x;
  const int d = blockIdx.x * 8 + (t >> 5);
  const int c = t & 31;
  if (d >= NN) return;
  const int jb = rowptr[d], je = rowptr[d + 1];
  float acc = 0.f;
#pragma unroll 4
  for (int j = jb; j < je; j++) {
    acc += alpha2[j] * xlr2[csr_s[j] * 64 + c];
  }
  float v = acc + b2[c];
  float mx = v;
#pragma unroll
  for (int off = 16; off > 0; off >>= 1) mx = fmaxf(mx, __shfl_xor(mx, off));
  float ex = __expf(v - mx);
  float sum = ex;
#pragma unroll
  for (int off = 16; off > 0; off >>= 1) sum += __shfl_xor(sum, off);
  out[d * 32 + c] = v - mx - logf(sum);
}

extern "C" void kernel_launch(void* const* d_in, const int* in_sizes, int n_in,
                              void* d_out, int out_size, void* d_ws, size_t ws_size,
                              hipStream_t stream) {
  const float* x    = (const float*)d_in[0];
  const int*   ei   = (const int*)d_in[1];
  const float* W1l  = (const float*)d_in[2];
  const float* W1r  = (const float*)d_in[3];
  const float* att1 = (const float*)d_in[4];
  const float* b1   = (const float*)d_in[5];
  const float* W2l  = (const float*)d_in[6];
  const float* W2r  = (const float*)d_in[7];
  const float* att2 = (const float*)d_in[8];
  const float* b2   = (const float*)d_in[9];
  float* out = (float*)d_out;

  // workspace layout
  short* Xb   = (short*)d_ws;                        // MPAD*256
  short* Wt1  = Xb + (size_t)MPAD * 256;             // 2048*256
  short* Wt2  = Wt1 + (size_t)2048 * 256;            // 128*1024
  short* xlr  = Wt2 + (size_t)128 * 1024;            // NN*2048 bf16 (xl | xr)
  short* h1b  = xlr + (size_t)NN * 2048;             // MPAD*1024 bf16
  float* xlr2 = (float*)(h1b + (size_t)MPAD * 1024); // NN*64
  float* alar = xlr2 + (size_t)NN * 64;              // NN*16
  float* sc1  = alar + (size_t)NN * 16;              // NE*8 (scores -> alphas)
  float* sc2  = sc1 + (size_t)NE * 8;                // NE
  int* deg    = (int*)(sc2 + NE);                    // NN
  int* rowptr = deg + NN;                            // NN+1
  int* cursor = rowptr + NN + 1;                     // NN
  int* csr_s  = cursor + NN;                         // NE
  int* csr_d  = csr_s + NE;                          // NE

  const int* src = ei;
  const int* dst = ei + NE;

  // CSR build (dst-sorted src/dst arrays)
  hipMemsetAsync(deg, 0, NN * sizeof(int), stream);
  deg_hist<<<(NE + 255) / 256, 256, 0, stream>>>(dst, deg);
  scan_rowptr<<<1, 1024, 0, stream>>>(deg, rowptr, cursor);
  csr_fill<<<(NE + 255) / 256, 256, 0, stream>>>(src, dst, cursor, csr_s, csr_d);

  // conversions
  cvt_x<<<(MPAD * 256 / 4 + 255) / 256, 256, 0, stream>>>(x, Xb);
  {
    dim3 g(2048 / 32, 256 / 32);
    transpose_cvt_dual<<<g, 256, 0, stream>>>(W1l, W1r, Wt1, 256, 1024);
  }
  {
    dim3 g(64 / 32, 1024 / 32);
    transpose_cvt_dual<<<g, 256, 0, stream>>>(W2l, W2r, Wt2, 1024, 32);
    hipMemsetAsync(Wt2 + (size_t)64 * 1024, 0, (size_t)64 * 1024 * sizeof(short), stream);
  }

  // layer-1 GEMM -> xlr bf16 [NN][2048]
  {
    dim3 g(2048 / 128, MPAD / 128);
    gemm_bf16<1><<<g, 256, 0, stream>>>(Xb, Wt1, xlr, NN, 256, 2048, 2048);
  }

  // per-node att dots (separable 0.6u part of lrelu)
  prep_alar<<<NN, 256, 0, stream>>>(xlr, att1, alar);

  // layer-1 attention: flat phases
  score1<<<NE / 4, 256, 0, stream>>>(csr_s, csr_d, xlr, att1, alar, sc1);
  softmax1<<<(NN * H + 255) / 256, 256, 0, stream>>>(rowptr, sc1);
  agg1_fast<<<NN / 2, 256, 0, stream>>>(rowptr, csr_s, sc1, xlr, b1, h1b);

  // layer-2 GEMM -> xlr2 fp32 [NN][64]
  {
    dim3 g(1, MPAD / 128);
    gemm_bf16<0><<<g, 256, 0, stream>>>(h1b, Wt2, xlr2, NN, 1024, 64, 64);
  }

  // layer-2 attention: flat phases
  score2<<<NE / 8, 256, 0, stream>>>(csr_s, csr_d, xlr2, att2, sc2);
  softmax2<<<(NN + 255) / 256, 256, 0, stream>>>(rowptr, sc2);
  agg2_fast<<<(NN + 7) / 8, 256, 0, stream>>>(rowptr, csr_s, sc2, xlr2, b2, out);
}

// Round 8
// 335.094 us; speedup vs baseline: 1.2721x; 1.0733x over previous
//
#include <hip/hip_runtime.h>
#include <hip/hip_bf16.h>

constexpr int NN   = 10000;
constexpr int NE   = 160000;
constexpr int INC  = 256;
constexpr int H    = 8;
constexpr int D1   = 1024;     // 8 heads x 128
constexpr int OUTC = 32;
constexpr int MPAD = 10112;    // 79 * 128
constexpr float NEG_SLOPE = 0.2f;

typedef __attribute__((ext_vector_type(8))) short bf16x8;
typedef __attribute__((ext_vector_type(4))) float f32x4;

__device__ __forceinline__ unsigned short f2b(float f) {
  unsigned u = __float_as_uint(f);
  unsigned r = (u + 0x7fffu + ((u >> 16) & 1u)) >> 16;
  return (unsigned short)r;
}
__device__ __forceinline__ float b2f_lo(unsigned u) { return __uint_as_float(u << 16); }
__device__ __forceinline__ float b2f_hi(unsigned u) { return __uint_as_float(u & 0xffff0000u); }
__device__ __forceinline__ float lrelu(float a) { return fmaxf(a, 0.f) + NEG_SLOPE * fminf(a, 0.f); }

// ---------------- CSR build ----------------
__global__ void deg_hist(const int* __restrict__ dst, int* __restrict__ deg) {
  int e = blockIdx.x * 256 + threadIdx.x;
  if (e < NE) atomicAdd(&deg[dst[e]], 1);
}

// parallel exclusive scan: 1 block x 1024 threads, 10 elems/thread.
__global__ __launch_bounds__(1024) void scan_rowptr(const int* __restrict__ deg,
                                                    int* __restrict__ rowptr,
                                                    int* __restrict__ cursor) {
  __shared__ int wsum[16];
  const int t = threadIdx.x;
  const int lane = t & 63, w = t >> 6;
  const int base = t * 10;
  int v[10];
  int tot = 0;
#pragma unroll
  for (int i = 0; i < 10; i++) {
    int idx = base + i;
    int x = (idx < NN) ? deg[idx] : 0;
    v[i] = tot;
    tot += x;
  }
  int ws = tot;
#pragma unroll
  for (int off = 1; off < 64; off <<= 1) {
    int u = __shfl_up(ws, off);
    if (lane >= off) ws += u;
  }
  if (lane == 63) wsum[w] = ws;
  __syncthreads();
  if (w == 0) {
    int x = (lane < 16) ? wsum[lane] : 0;
#pragma unroll
    for (int off = 1; off < 16; off <<= 1) {
      int u = __shfl_up(x, off);
      if (lane >= off) x += u;
    }
    if (lane < 16) wsum[lane] = x;
  }
  __syncthreads();
  const int wbase = (w > 0) ? wsum[w - 1] : 0;
  const int tbase = wbase + ws - tot;
#pragma unroll
  for (int i = 0; i < 10; i++) {
    int idx = base + i;
    if (idx < NN) {
      int r = tbase + v[i];
      rowptr[idx] = r;
      cursor[idx] = r;
    }
  }
  if (t == 1023) rowptr[NN] = wbase + ws;
}

__global__ void csr_fill(const int* __restrict__ src, const int* __restrict__ dst,
                         int* __restrict__ cursor,
                         int* __restrict__ csr_s, int* __restrict__ csr_d) {
  int e = blockIdx.x * 256 + threadIdx.x;
  if (e >= NE) return;
  int d = dst[e];
  int pos = atomicAdd(&cursor[d], 1);
  csr_s[pos] = src[e];
  csr_d[pos] = d;
}

// ---------------- conversions ----------------
__global__ void cvt_x(const float* __restrict__ x, short* __restrict__ Xb) {
  int i = blockIdx.x * 256 + threadIdx.x;
  int base = i * 4;
  if (base >= MPAD * INC) return;
  ushort4 o;
  if (base < NN * INC) {
    float4 v = *(const float4*)(x + base);
    o.x = f2b(v.x); o.y = f2b(v.y); o.z = f2b(v.z); o.w = f2b(v.w);
  } else {
    o.x = o.y = o.z = o.w = 0;
  }
  *(ushort4*)(Xb + base) = o;
}

// dual-source transpose+convert
__global__ __launch_bounds__(256) void transpose_cvt_dual(const float* __restrict__ srcA,
                                                          const float* __restrict__ srcB,
                                                          short* __restrict__ dst,
                                                          int K, int NsrcHalf) {
  __shared__ float tile[32][33];
  int tx = threadIdx.x & 31, ty = threadIdx.x >> 5;
  int nb = blockIdx.x * 32, kb = blockIdx.y * 32;
  const float* src = srcA;
  int nloc = nb;
  if (nb >= NsrcHalf) { src = srcB; nloc = nb - NsrcHalf; }
#pragma unroll
  for (int i = 0; i < 4; i++)
    tile[ty + i * 8][tx] = src[(size_t)(kb + ty + i * 8) * NsrcHalf + nloc + tx];
  __syncthreads();
#pragma unroll
  for (int i = 0; i < 4; i++)
    dst[(size_t)(nb + ty + i * 8) * K + kb + tx] = (short)f2b(tile[tx][ty + i * 8]);
}

// ---------------- layer-1 GEMM, fused epilogue (coalesced bf16 store + alar dots) ----------------
// C[MPAD][2048] tile 128x128; grid (16, 79). Block (bx,by) covers cols bx*128..+127
// = exactly one head slot (bx<8: xl head bx; bx>=8: xr head bx-8) -> writes
// alar[n*16+bx] = sum_c att[(c&1023)]*C[n][c] for its rows.
__global__ __launch_bounds__(256) void gemm1_fused(const short* __restrict__ Xb,
                                                   const short* __restrict__ Wt,
                                                   const float* __restrict__ att,
                                                   short* __restrict__ xlr,
                                                   float* __restrict__ alar) {
  __shared__ short As[4096];
  __shared__ short Bs[4096];
  __shared__ short Cs[128][136];
  const int t = threadIdx.x;
  const int lane = t & 63;
  const int w = t >> 6;
  const int wr = w >> 1, wc = w & 1;
  const int row0 = blockIdx.y * 128;
  const int col0 = blockIdx.x * 128;
  const int r_st = t & 127;
  const int kc_st = t >> 7;
  f32x4 acc[4][4] = {};
  for (int k0 = 0; k0 < 256; k0 += 32) {
    bf16x8 va0 = *(const bf16x8*)(Xb + (size_t)(row0 + r_st) * 256 + k0 + kc_st * 8);
    bf16x8 va1 = *(const bf16x8*)(Xb + (size_t)(row0 + r_st) * 256 + k0 + (kc_st + 2) * 8);
    bf16x8 vb0 = *(const bf16x8*)(Wt + (size_t)(col0 + r_st) * 256 + k0 + kc_st * 8);
    bf16x8 vb1 = *(const bf16x8*)(Wt + (size_t)(col0 + r_st) * 256 + k0 + (kc_st + 2) * 8);
    __syncthreads();
    *(bf16x8*)&As[(kc_st)     * 1024 + r_st * 8] = va0;
    *(bf16x8*)&As[(kc_st + 2) * 1024 + r_st * 8] = va1;
    *(bf16x8*)&Bs[(kc_st)     * 1024 + r_st * 8] = vb0;
    *(bf16x8*)&Bs[(kc_st + 2) * 1024 + r_st * 8] = vb1;
    __syncthreads();
    bf16x8 af[4], bfr[4];
#pragma unroll
    for (int i = 0; i < 4; i++)
      af[i] = *(const bf16x8*)&As[(lane >> 4) * 1024 + (wr * 64 + i * 16 + (lane & 15)) * 8];
#pragma unroll
    for (int j = 0; j < 4; j++)
      bfr[j] = *(const bf16x8*)&Bs[(lane >> 4) * 1024 + (wc * 64 + j * 16 + (lane & 15)) * 8];
#pragma unroll
    for (int i = 0; i < 4; i++)
#pragma unroll
      for (int j = 0; j < 4; j++)
        acc[i][j] = __builtin_amdgcn_mfma_f32_16x16x32_bf16(af[i], bfr[j], acc[i][j], 0, 0, 0);
  }
  // stage C tile to LDS as bf16 (C/D layout: col=lane&15, row=(lane>>4)*4+reg)
  __syncthreads();   // As/Bs reads done; Cs region distinct but sync before cross-read below anyway
#pragma unroll
  for (int i = 0; i < 4; i++) {
#pragma unroll
    for (int reg = 0; reg < 4; reg++) {
      int r = wr * 64 + i * 16 + (lane >> 4) * 4 + reg;
#pragma unroll
      for (int j = 0; j < 4; j++)
        Cs[r][wc * 64 + j * 16 + (lane & 15)] = (short)f2b(acc[i][j][reg]);
    }
  }
  __syncthreads();
  // coalesced write-out + per-row att dot (2 threads per row)
  const int r = t >> 1, half = t & 1;
  const int gr = row0 + r;
  float dot = 0.f;
  if (gr < NN) {
#pragma unroll
    for (int chunk = 0; chunk < 8; chunk++) {
      const int cloc = half * 64 + chunk * 8;
      uint4 v = *(const uint4*)&Cs[r][cloc];
      *(uint4*)(xlr + (size_t)gr * 2048 + col0 + cloc) = v;
      const int ca = (col0 + cloc) & 1023;
      const float4 a0 = *(const float4*)(att + ca);
      const float4 a1 = *(const float4*)(att + ca + 4);
      dot += b2f_lo(v.x) * a0.x + b2f_hi(v.x) * a0.y
           + b2f_lo(v.y) * a0.z + b2f_hi(v.y) * a0.w
           + b2f_lo(v.z) * a1.x + b2f_hi(v.z) * a1.y
           + b2f_lo(v.w) * a1.z + b2f_hi(v.w) * a1.w;
    }
  }
  dot += __shfl_xor(dot, 1);
  if (half == 0 && gr < NN) alar[gr * 16 + blockIdx.x] = dot;
}

// ---------------- layer-2 GEMM: [MPAD x 1024] x [64 x 1024]^T -> fp32 [NN][64] ----------------
// tile 64x64, grid (1, 158), 4 waves (2x2), BK=32.
__global__ __launch_bounds__(256) void gemm2_64(const short* __restrict__ h1b,
                                                const short* __restrict__ Wt2,
                                                float* __restrict__ xlr2) {
  __shared__ short As[4][64][8];
  __shared__ short Bs[4][64][8];
  const int t = threadIdx.x;
  const int lane = t & 63;
  const int wv = t >> 6;
  const int wr = wv >> 1, wc = wv & 1;
  const int row0 = blockIdx.y * 64;
  const int r_st = t & 63;
  const int kc2 = t >> 6;
  f32x4 acc[2][2] = {};
  for (int k0 = 0; k0 < 1024; k0 += 32) {
    bf16x8 va = *(const bf16x8*)(h1b + (size_t)(row0 + r_st) * 1024 + k0 + kc2 * 8);
    bf16x8 vb = *(const bf16x8*)(Wt2 + (size_t)r_st * 1024 + k0 + kc2 * 8);
    __syncthreads();
    *(bf16x8*)&As[kc2][r_st][0] = va;
    *(bf16x8*)&Bs[kc2][r_st][0] = vb;
    __syncthreads();
    const int ks = lane >> 4;
    bf16x8 af0 = *(const bf16x8*)&As[ks][wr * 32 + (lane & 15)][0];
    bf16x8 af1 = *(const bf16x8*)&As[ks][wr * 32 + 16 + (lane & 15)][0];
    bf16x8 bf0 = *(const bf16x8*)&Bs[ks][wc * 32 + (lane & 15)][0];
    bf16x8 bf1 = *(const bf16x8*)&Bs[ks][wc * 32 + 16 + (lane & 15)][0];
    acc[0][0] = __builtin_amdgcn_mfma_f32_16x16x32_bf16(af0, bf0, acc[0][0], 0, 0, 0);
    acc[0][1] = __builtin_amdgcn_mfma_f32_16x16x32_bf16(af0, bf1, acc[0][1], 0, 0, 0);
    acc[1][0] = __builtin_amdgcn_mfma_f32_16x16x32_bf16(af1, bf0, acc[1][0], 0, 0, 0);
    acc[1][1] = __builtin_amdgcn_mfma_f32_16x16x32_bf16(af1, bf1, acc[1][1], 0, 0, 0);
  }
#pragma unroll
  for (int i = 0; i < 2; i++) {
#pragma unroll
    for (int reg = 0; reg < 4; reg++) {
      int gr = row0 + wr * 32 + i * 16 + (lane >> 4) * 4 + reg;
      if (gr < NN) {
#pragma unroll
        for (int j = 0; j < 2; j++) {
          int gc = wc * 32 + j * 16 + (lane & 15);
          xlr2[(size_t)gr * 64 + gc] = acc[i][j][reg];
        }
      }
    }
  }
}

// ---------------- layer-1 scores: 2 edges per wave for memory ILP ----------------
__device__ __forceinline__ float score_dot(uint4 la, uint4 lb, uint4 ra, uint4 rb,
                                           float4 t0, float4 t1, float4 t2, float4 t3) {
  float p;
  p  = fabsf(b2f_lo(la.x) + b2f_lo(ra.x)) * t0.x;
  p += fabsf(b2f_hi(la.x) + b2f_hi(ra.x)) * t0.y;
  p += fabsf(b2f_lo(la.y) + b2f_lo(ra.y)) * t0.z;
  p += fabsf(b2f_hi(la.y) + b2f_hi(ra.y)) * t0.w;
  p += fabsf(b2f_lo(la.z) + b2f_lo(ra.z)) * t1.x;
  p += fabsf(b2f_hi(la.z) + b2f_hi(ra.z)) * t1.y;
  p += fabsf(b2f_lo(la.w) + b2f_lo(ra.w)) * t1.z;
  p += fabsf(b2f_hi(la.w) + b2f_hi(ra.w)) * t1.w;
  p += fabsf(b2f_lo(lb.x) + b2f_lo(rb.x)) * t2.x;
  p += fabsf(b2f_hi(lb.x) + b2f_hi(rb.x)) * t2.y;
  p += fabsf(b2f_lo(lb.y) + b2f_lo(rb.y)) * t2.z;
  p += fabsf(b2f_hi(lb.y) + b2f_hi(rb.y)) * t2.w;
  p += fabsf(b2f_lo(lb.z) + b2f_lo(rb.z)) * t3.x;
  p += fabsf(b2f_hi(lb.z) + b2f_hi(rb.z)) * t3.y;
  p += fabsf(b2f_lo(lb.w) + b2f_lo(rb.w)) * t3.z;
  p += fabsf(b2f_hi(lb.w) + b2f_hi(rb.w)) * t3.w;
  return p;
}

__global__ __launch_bounds__(256) void score1(const int* __restrict__ csr_s, const int* __restrict__ csr_d,
                                              const short* __restrict__ xlr, const float* __restrict__ att,
                                              const float* __restrict__ alar, float* __restrict__ sc1) {
  const int lane = threadIdx.x & 63;
  const int j0 = (blockIdx.x * 4 + (threadIdx.x >> 6)) * 2;   // grid = NE/8, NE%8==0
  const int s0 = csr_s[j0], d0 = csr_d[j0];
  const int s1 = csr_s[j0 + 1], d1 = csr_d[j0 + 1];
  const short* xls0 = xlr + (size_t)s0 * 2048 + lane * 16;
  const short* xrd0 = xlr + (size_t)d0 * 2048 + 1024 + lane * 16;
  const short* xls1 = xlr + (size_t)s1 * 2048 + lane * 16;
  const short* xrd1 = xlr + (size_t)d1 * 2048 + 1024 + lane * 16;
  uint4 la0 = *(const uint4*)xls0;
  uint4 lb0 = *(const uint4*)(xls0 + 8);
  uint4 ra0 = *(const uint4*)xrd0;
  uint4 rb0 = *(const uint4*)(xrd0 + 8);
  uint4 la1 = *(const uint4*)xls1;
  uint4 lb1 = *(const uint4*)(xls1 + 8);
  uint4 ra1 = *(const uint4*)xrd1;
  uint4 rb1 = *(const uint4*)(xrd1 + 8);
  const float4* a4 = (const float4*)(att + lane * 16);
  float4 t0 = a4[0], t1 = a4[1], t2 = a4[2], t3 = a4[3];
  float p0 = score_dot(la0, lb0, ra0, rb0, t0, t1, t2, t3);
  float p1 = score_dot(la1, lb1, ra1, rb1, t0, t1, t2, t3);
#pragma unroll
  for (int off = 1; off < 8; off <<= 1) {
    p0 += __shfl_xor(p0, off);
    p1 += __shfl_xor(p1, off);
  }
  if ((lane & 7) == 0) {
    int h = lane >> 3;
    sc1[j0 * 8 + h]     = 0.4f * p0 + 0.6f * (alar[s0 * 16 + h] + alar[d0 * 16 + 8 + h]);
    sc1[j0 * 8 + 8 + h] = 0.4f * p1 + 0.6f * (alar[s1 * 16 + h] + alar[d1 * 16 + 8 + h]);
  }
}

// ---------------- layer-1 segment softmax (thread per (dst,head)) ----------------
__global__ void softmax1(const int* __restrict__ rowptr, float* __restrict__ sc1) {
  int i = blockIdx.x * 256 + threadIdx.x;
  if (i >= NN * H) return;
  int d = i >> 3, h = i & 7;
  int jb = rowptr[d], je = rowptr[d + 1];
  if (jb == je) return;
  float m = -3.4e38f;
  for (int j = jb; j < je; j++) m = fmaxf(m, sc1[j * 8 + h]);
  float s = 0.f;
  for (int j = jb; j < je; j++) s += __expf(sc1[j * 8 + h] - m);
  float inv = 1.f / (s + 1e-16f);
  for (int j = jb; j < je; j++) sc1[j * 8 + h] = __expf(sc1[j * 8 + h] - m) * inv;
}

// ---------------- layer-1 aggregation: 2 waves per dst, wave-streaming ----------------
__global__ __launch_bounds__(256) void agg1_fast(const int* __restrict__ rowptr, const int* __restrict__ csr_s,
                                                 const float* __restrict__ alpha, const short* __restrict__ xlr,
                                                 const float* __restrict__ b1, short* __restrict__ h1b) {
  const int widx = threadIdx.x >> 6;
  const int lane = threadIdx.x & 63;
  const int d = blockIdx.x * 2 + (widx >> 1);
  const int ch = (widx & 1) * 512 + lane * 8;
  const int h = ch >> 7;
  const int jb = rowptr[d], je = rowptr[d + 1];
  float a0 = 0.f, a1 = 0.f, a2 = 0.f, a3 = 0.f, a4 = 0.f, a5 = 0.f, a6 = 0.f, a7 = 0.f;
#pragma unroll 4
  for (int j = jb; j < je; j++) {
    int s = csr_s[j];
    float al = alpha[j * 8 + h];
    uint4 v = *(const uint4*)(xlr + (size_t)s * 2048 + ch);
    a0 += al * b2f_lo(v.x); a1 += al * b2f_hi(v.x);
    a2 += al * b2f_lo(v.y); a3 += al * b2f_hi(v.y);
    a4 += al * b2f_lo(v.z); a5 += al * b2f_hi(v.z);
    a6 += al * b2f_lo(v.w); a7 += al * b2f_hi(v.w);
  }
  const float4 b0 = *(const float4*)(b1 + ch);
  const float4 b4 = *(const float4*)(b1 + ch + 4);
  a0 += b0.x; a1 += b0.y; a2 += b0.z; a3 += b0.w;
  a4 += b4.x; a5 += b4.y; a6 += b4.z; a7 += b4.w;
  a0 = a0 > 0.f ? a0 : expm1f(a0);
  a1 = a1 > 0.f ? a1 : expm1f(a1);
  a2 = a2 > 0.f ? a2 : expm1f(a2);
  a3 = a3 > 0.f ? a3 : expm1f(a3);
  a4 = a4 > 0.f ? a4 : expm1f(a4);
  a5 = a5 > 0.f ? a5 : expm1f(a5);
  a6 = a6 > 0.f ? a6 : expm1f(a6);
  a7 = a7 > 0.f ? a7 : expm1f(a7);
  ushort4 o0, o4;
  o0.x = f2b(a0); o0.y = f2b(a1); o0.z = f2b(a2); o0.w = f2b(a3);
  o4.x = f2b(a4); o4.y = f2b(a5); o4.z = f2b(a6); o4.w = f2b(a7);
  *(ushort4*)(h1b + (size_t)d * 1024 + ch) = o0;
  *(ushort4*)(h1b + (size_t)d * 1024 + ch + 4) = o4;
}

// ---------------- layer-2 scores, CSR-ordered (32 lanes per slot) ----------------
__global__ __launch_bounds__(256) void score2(const int* __restrict__ csr_s, const int* __restrict__ csr_d,
                                              const float* __restrict__ xlr2, const float* __restrict__ att2,
                                              float* __restrict__ sc2) {
  const int t = threadIdx.x;
  const int j = blockIdx.x * 8 + (t >> 5);
  const int c = t & 31;
  if (j >= NE) return;
  int s = csr_s[j], d = csr_d[j];
  float p = att2[c] * lrelu(xlr2[s * 64 + c] + xlr2[d * 64 + 32 + c]);
#pragma unroll
  for (int off = 16; off > 0; off >>= 1) p += __shfl_xor(p, off);
  if (c == 0) sc2[j] = p;
}

// ---------------- layer-2 segment softmax (thread per dst) ----------------
__global__ void softmax2(const int* __restrict__ rowptr, float* __restrict__ sc2) {
  int d = blockIdx.x * 256 + threadIdx.x;
  if (d >= NN) return;
  int jb = rowptr[d], je = rowptr[d + 1];
  if (jb == je) return;
  float m = -3.4e38f;
  for (int j = jb; j < je; j++) m = fmaxf(m, sc2[j]);
  float s = 0.f;
  for (int j = jb; j < je; j++) s += __expf(sc2[j] - m);
  float inv = 1.f / (s + 1e-16f);
  for (int j = jb; j < je; j++) sc2[j] = __expf(sc2[j] - m) * inv;
}

// ---------------- layer-2 aggregation + bias + log_softmax (32 lanes per dst) ----------------
__global__ __launch_bounds__(256) void agg2_fast(const int* __restrict__ rowptr, const int* __restrict__ csr_s,
                                                 const float* __restrict__ alpha2, const float* __restrict__ xlr2,
                                                 const float* __restrict__ b2, float* __restrict__ out) {
  const int t = threadIdx.x;
  const int d = blockIdx.x * 8 + (t >> 5);
  const int c = t & 31;
  if (d >= NN) return;
  const int jb = rowptr[d], je = rowptr[d + 1];
  float acc = 0.f;
#pragma unroll 4
  for (int j = jb; j < je; j++) {
    acc += alpha2[j] * xlr2[csr_s[j] * 64 + c];
  }
  float v = acc + b2[c];
  float mx = v;
#pragma unroll
  for (int off = 16; off > 0; off >>= 1) mx = fmaxf(mx, __shfl_xor(mx, off));
  float ex = __expf(v - mx);
  float sum = ex;
#pragma unroll
  for (int off = 16; off > 0; off >>= 1) sum += __shfl_xor(sum, off);
  out[d * 32 + c] = v - mx - logf(sum);
}

extern "C" void kernel_launch(void* const* d_in, const int* in_sizes, int n_in,
                              void* d_out, int out_size, void* d_ws, size_t ws_size,
                              hipStream_t stream) {
  const float* x    = (const float*)d_in[0];
  const int*   ei   = (const int*)d_in[1];
  const float* W1l  = (const float*)d_in[2];
  const float* W1r  = (const float*)d_in[3];
  const float* att1 = (const float*)d_in[4];
  const float* b1   = (const float*)d_in[5];
  const float* W2l  = (const float*)d_in[6];
  const float* W2r  = (const float*)d_in[7];
  const float* att2 = (const float*)d_in[8];
  const float* b2   = (const float*)d_in[9];
  float* out = (float*)d_out;

  // workspace layout
  short* Xb   = (short*)d_ws;                        // MPAD*256
  short* Wt1  = Xb + (size_t)MPAD * 256;             // 2048*256
  short* Wt2  = Wt1 + (size_t)2048 * 256;            // 64*1024
  short* xlr  = Wt2 + (size_t)64 * 1024;             // NN*2048 bf16 (xl | xr)
  short* h1b  = xlr + (size_t)NN * 2048;             // MPAD*1024 bf16
  float* xlr2 = (float*)(h1b + (size_t)MPAD * 1024); // NN*64
  float* alar = xlr2 + (size_t)NN * 64;              // NN*16
  float* sc1  = alar + (size_t)NN * 16;              // NE*8 (scores -> alphas)
  float* sc2  = sc1 + (size_t)NE * 8;                // NE
  int* deg    = (int*)(sc2 + NE);                    // NN
  int* rowptr = deg + NN;                            // NN+1
  int* cursor = rowptr + NN + 1;                     // NN
  int* csr_s  = cursor + NN;                         // NE
  int* csr_d  = csr_s + NE;                          // NE

  const int* src = ei;
  const int* dst = ei + NE;

  // CSR build (dst-sorted src/dst arrays)
  hipMemsetAsync(deg, 0, NN * sizeof(int), stream);
  deg_hist<<<(NE + 255) / 256, 256, 0, stream>>>(dst, deg);
  scan_rowptr<<<1, 1024, 0, stream>>>(deg, rowptr, cursor);
  csr_fill<<<(NE + 255) / 256, 256, 0, stream>>>(src, dst, cursor, csr_s, csr_d);

  // conversions
  cvt_x<<<(MPAD * 256 / 4 + 255) / 256, 256, 0, stream>>>(x, Xb);
  {
    dim3 g(2048 / 32, 256 / 32);
    transpose_cvt_dual<<<g, 256, 0, stream>>>(W1l, W1r, Wt1, 256, 1024);
  }
  {
    dim3 g(64 / 32, 1024 / 32);
    transpose_cvt_dual<<<g, 256, 0, stream>>>(W2l, W2r, Wt2, 1024, 32);
  }

  // layer-1 GEMM -> xlr bf16 [NN][2048] + alar (fused)
  {
    dim3 g(16, 79);
    gemm1_fused<<<g, 256, 0, stream>>>(Xb, Wt1, att1, xlr, alar);
  }

  // layer-1 attention: flat phases
  score1<<<NE / 8, 256, 0, stream>>>(csr_s, csr_d, xlr, att1, alar, sc1);
  softmax1<<<(NN * H + 255) / 256, 256, 0, stream>>>(rowptr, sc1);
  agg1_fast<<<NN / 2, 256, 0, stream>>>(rowptr, csr_s, sc1, xlr, b1, h1b);

  // layer-2 GEMM -> xlr2 fp32 [NN][64]
  {
    dim3 g(1, MPAD / 64);
    gemm2_64<<<g, 256, 0, stream>>>(h1b, Wt2, xlr2);
  }

  // layer-2 attention: flat phases
  score2<<<NE / 8, 256, 0, stream>>>(csr_s, csr_d, xlr2, att2, sc2);
  softmax2<<<(NN + 255) / 256, 256, 0, stream>>>(rowptr, sc2);
  agg2_fast<<<(NN + 7) / 8, 256, 0, stream>>>(rowptr, csr_s, sc2, xlr2, b2, out);
}

// Round 9
// 299.418 us; speedup vs baseline: 1.4236x; 1.1192x over previous
//
#include <hip/hip_runtime.h>
#include <hip/hip_bf16.h>

constexpr int NN   = 10000;
constexpr int NE   = 160000;
constexpr int INC  = 256;
constexpr int H    = 8;
constexpr int D1   = 1024;     // 8 heads x 128
constexpr int OUTC = 32;
constexpr int MPAD = 10112;    // 79 * 128
constexpr float NEG_SLOPE = 0.2f;

typedef __attribute__((ext_vector_type(8))) short bf16x8;
typedef __attribute__((ext_vector_type(4))) float f32x4;

__device__ __forceinline__ unsigned short f2b(float f) {
  unsigned u = __float_as_uint(f);
  unsigned r = (u + 0x7fffu + ((u >> 16) & 1u)) >> 16;
  return (unsigned short)r;
}
__device__ __forceinline__ float b2f_lo(unsigned u) { return __uint_as_float(u << 16); }
__device__ __forceinline__ float b2f_hi(unsigned u) { return __uint_as_float(u & 0xffff0000u); }
__device__ __forceinline__ float lrelu(float a) { return fmaxf(a, 0.f) + NEG_SLOPE * fminf(a, 0.f); }

// ---------------- uber prep: x->bf16 pad, W1 transpose, W2 transpose, deg hist ----------------
constexpr int NB_CVT = MPAD * INC / 4 / 256;        // 2528
constexpr int NB_W1X = 2048 / 32;                   // 64
constexpr int NB_W1  = NB_W1X * (256 / 32);         // 512
constexpr int NB_W2X = 64 / 32;                     // 2
constexpr int NB_W2  = NB_W2X * (1024 / 32);        // 64
constexpr int NB_DEG = (NE + 255) / 256;            // 625

__device__ __forceinline__ void transpose_body(const float* __restrict__ srcA,
                                               const float* __restrict__ srcB,
                                               short* __restrict__ dst,
                                               int K, int NsrcHalf, int bx, int by,
                                               int tx, int ty) {
  __shared__ float tile[32][33];
  int nb = bx * 32, kb = by * 32;
  const float* src = srcA;
  int nloc = nb;
  if (nb >= NsrcHalf) { src = srcB; nloc = nb - NsrcHalf; }
#pragma unroll
  for (int i = 0; i < 4; i++)
    tile[ty + i * 8][tx] = src[(size_t)(kb + ty + i * 8) * NsrcHalf + nloc + tx];
  __syncthreads();
#pragma unroll
  for (int i = 0; i < 4; i++)
    dst[(size_t)(nb + ty + i * 8) * K + kb + tx] = (short)f2b(tile[tx][ty + i * 8]);
}

__global__ __launch_bounds__(256) void prep(const float* __restrict__ x, short* __restrict__ Xb,
                                            const float* __restrict__ W1l, const float* __restrict__ W1r,
                                            short* __restrict__ Wt1,
                                            const float* __restrict__ W2l, const float* __restrict__ W2r,
                                            short* __restrict__ Wt2,
                                            const int* __restrict__ dst, int* __restrict__ deg) {
  const int b = blockIdx.x;
  const int t = threadIdx.x;
  if (b < NB_CVT) {
    int base = (b * 256 + t) * 4;
    ushort4 o;
    if (base < NN * INC) {
      float4 v = *(const float4*)(x + base);
      o.x = f2b(v.x); o.y = f2b(v.y); o.z = f2b(v.z); o.w = f2b(v.w);
    } else {
      o.x = o.y = o.z = o.w = 0;
    }
    *(ushort4*)(Xb + base) = o;
  } else if (b < NB_CVT + NB_W1) {
    int bb = b - NB_CVT;
    transpose_body(W1l, W1r, Wt1, 256, 1024, bb % NB_W1X, bb / NB_W1X, t & 31, t >> 5);
  } else if (b < NB_CVT + NB_W1 + NB_W2) {
    int bb = b - NB_CVT - NB_W1;
    transpose_body(W2l, W2r, Wt2, 1024, 32, bb % NB_W2X, bb / NB_W2X, t & 31, t >> 5);
  } else {
    int e = (b - NB_CVT - NB_W1 - NB_W2) * 256 + t;
    if (e < NE) atomicAdd(&deg[dst[e]], 1);
  }
}

// ---------------- parallel exclusive scan: 1 block x 1024 threads ----------------
__global__ __launch_bounds__(1024) void scan_rowptr(const int* __restrict__ deg,
                                                    int* __restrict__ rowptr,
                                                    int* __restrict__ cursor) {
  __shared__ int wsum[16];
  const int t = threadIdx.x;
  const int lane = t & 63, w = t >> 6;
  const int base = t * 10;
  int v[10];
  int tot = 0;
#pragma unroll
  for (int i = 0; i < 10; i++) {
    int idx = base + i;
    int x = (idx < NN) ? deg[idx] : 0;
    v[i] = tot;
    tot += x;
  }
  int ws = tot;
#pragma unroll
  for (int off = 1; off < 64; off <<= 1) {
    int u = __shfl_up(ws, off);
    if (lane >= off) ws += u;
  }
  if (lane == 63) wsum[w] = ws;
  __syncthreads();
  if (w == 0) {
    int x = (lane < 16) ? wsum[lane] : 0;
#pragma unroll
    for (int off = 1; off < 16; off <<= 1) {
      int u = __shfl_up(x, off);
      if (lane >= off) x += u;
    }
    if (lane < 16) wsum[lane] = x;
  }
  __syncthreads();
  const int wbase = (w > 0) ? wsum[w - 1] : 0;
  const int tbase = wbase + ws - tot;
#pragma unroll
  for (int i = 0; i < 10; i++) {
    int idx = base + i;
    if (idx < NN) {
      int r = tbase + v[i];
      rowptr[idx] = r;
      cursor[idx] = r;
    }
  }
  if (t == 1023) rowptr[NN] = wbase + ws;
}

__global__ void csr_fill(const int* __restrict__ src, const int* __restrict__ dst,
                         int* __restrict__ cursor, int* __restrict__ csr_s) {
  int e = blockIdx.x * 256 + threadIdx.x;
  if (e >= NE) return;
  int pos = atomicAdd(&cursor[dst[e]], 1);
  csr_s[pos] = src[e];
}

// ---------------- layer-1 GEMM, fused epilogue (coalesced bf16 store + alar dots) ----------------
__global__ __launch_bounds__(256) void gemm1_fused(const short* __restrict__ Xb,
                                                   const short* __restrict__ Wt,
                                                   const float* __restrict__ att,
                                                   short* __restrict__ xlr,
                                                   float* __restrict__ alar) {
  __shared__ short As[4096];
  __shared__ short Bs[4096];
  __shared__ short Cs[128][136];
  const int t = threadIdx.x;
  const int lane = t & 63;
  const int w = t >> 6;
  const int wr = w >> 1, wc = w & 1;
  const int row0 = blockIdx.y * 128;
  const int col0 = blockIdx.x * 128;
  const int r_st = t & 127;
  const int kc_st = t >> 7;
  f32x4 acc[4][4] = {};
  for (int k0 = 0; k0 < 256; k0 += 32) {
    bf16x8 va0 = *(const bf16x8*)(Xb + (size_t)(row0 + r_st) * 256 + k0 + kc_st * 8);
    bf16x8 va1 = *(const bf16x8*)(Xb + (size_t)(row0 + r_st) * 256 + k0 + (kc_st + 2) * 8);
    bf16x8 vb0 = *(const bf16x8*)(Wt + (size_t)(col0 + r_st) * 256 + k0 + kc_st * 8);
    bf16x8 vb1 = *(const bf16x8*)(Wt + (size_t)(col0 + r_st) * 256 + k0 + (kc_st + 2) * 8);
    __syncthreads();
    *(bf16x8*)&As[(kc_st)     * 1024 + r_st * 8] = va0;
    *(bf16x8*)&As[(kc_st + 2) * 1024 + r_st * 8] = va1;
    *(bf16x8*)&Bs[(kc_st)     * 1024 + r_st * 8] = vb0;
    *(bf16x8*)&Bs[(kc_st + 2) * 1024 + r_st * 8] = vb1;
    __syncthreads();
    bf16x8 af[4], bfr[4];
#pragma unroll
    for (int i = 0; i < 4; i++)
      af[i] = *(const bf16x8*)&As[(lane >> 4) * 1024 + (wr * 64 + i * 16 + (lane & 15)) * 8];
#pragma unroll
    for (int j = 0; j < 4; j++)
      bfr[j] = *(const bf16x8*)&Bs[(lane >> 4) * 1024 + (wc * 64 + j * 16 + (lane & 15)) * 8];
#pragma unroll
    for (int i = 0; i < 4; i++)
#pragma unroll
      for (int j = 0; j < 4; j++)
        acc[i][j] = __builtin_amdgcn_mfma_f32_16x16x32_bf16(af[i], bfr[j], acc[i][j], 0, 0, 0);
  }
  __syncthreads();
#pragma unroll
  for (int i = 0; i < 4; i++) {
#pragma unroll
    for (int reg = 0; reg < 4; reg++) {
      int r = wr * 64 + i * 16 + (lane >> 4) * 4 + reg;
#pragma unroll
      for (int j = 0; j < 4; j++)
        Cs[r][wc * 64 + j * 16 + (lane & 15)] = (short)f2b(acc[i][j][reg]);
    }
  }
  __syncthreads();
  const int r = t >> 1, half = t & 1;
  const int gr = row0 + r;
  float dot = 0.f;
  if (gr < NN) {
#pragma unroll
    for (int chunk = 0; chunk < 8; chunk++) {
      const int cloc = half * 64 + chunk * 8;
      uint4 v = *(const uint4*)&Cs[r][cloc];
      *(uint4*)(xlr + (size_t)gr * 2048 + col0 + cloc) = v;
      const int ca = (col0 + cloc) & 1023;
      const float4 a0 = *(const float4*)(att + ca);
      const float4 a1 = *(const float4*)(att + ca + 4);
      dot += b2f_lo(v.x) * a0.x + b2f_hi(v.x) * a0.y
           + b2f_lo(v.y) * a0.z + b2f_hi(v.y) * a0.w
           + b2f_lo(v.z) * a1.x + b2f_hi(v.z) * a1.y
           + b2f_lo(v.w) * a1.z + b2f_hi(v.w) * a1.w;
    }
  }
  dot += __shfl_xor(dot, 1);
  if (half == 0 && gr < NN) alar[gr * 16 + blockIdx.x] = dot;
}

// ---------------- layer-2 GEMM: [MPAD x 1024] x [64 x 1024]^T -> fp32 [NN][64] ----------------
__global__ __launch_bounds__(256) void gemm2_64(const short* __restrict__ h1b,
                                                const short* __restrict__ Wt2,
                                                float* __restrict__ xlr2) {
  __shared__ short As[4][64][8];
  __shared__ short Bs[4][64][8];
  const int t = threadIdx.x;
  const int lane = t & 63;
  const int wv = t >> 6;
  const int wr = wv >> 1, wc = wv & 1;
  const int row0 = blockIdx.y * 64;
  const int r_st = t & 63;
  const int kc2 = t >> 6;
  f32x4 acc[2][2] = {};
  for (int k0 = 0; k0 < 1024; k0 += 32) {
    bf16x8 va = *(const bf16x8*)(h1b + (size_t)(row0 + r_st) * 1024 + k0 + kc2 * 8);
    bf16x8 vb = *(const bf16x8*)(Wt2 + (size_t)r_st * 1024 + k0 + kc2 * 8);
    __syncthreads();
    *(bf16x8*)&As[kc2][r_st][0] = va;
    *(bf16x8*)&Bs[kc2][r_st][0] = vb;
    __syncthreads();
    const int ks = lane >> 4;
    bf16x8 af0 = *(const bf16x8*)&As[ks][wr * 32 + (lane & 15)][0];
    bf16x8 af1 = *(const bf16x8*)&As[ks][wr * 32 + 16 + (lane & 15)][0];
    bf16x8 bf0 = *(const bf16x8*)&Bs[ks][wc * 32 + (lane & 15)][0];
    bf16x8 bf1 = *(const bf16x8*)&Bs[ks][wc * 32 + 16 + (lane & 15)][0];
    acc[0][0] = __builtin_amdgcn_mfma_f32_16x16x32_bf16(af0, bf0, acc[0][0], 0, 0, 0);
    acc[0][1] = __builtin_amdgcn_mfma_f32_16x16x32_bf16(af0, bf1, acc[0][1], 0, 0, 0);
    acc[1][0] = __builtin_amdgcn_mfma_f32_16x16x32_bf16(af1, bf0, acc[1][0], 0, 0, 0);
    acc[1][1] = __builtin_amdgcn_mfma_f32_16x16x32_bf16(af1, bf1, acc[1][1], 0, 0, 0);
  }
#pragma unroll
  for (int i = 0; i < 2; i++) {
#pragma unroll
    for (int reg = 0; reg < 4; reg++) {
      int gr = row0 + wr * 32 + i * 16 + (lane >> 4) * 4 + reg;
      if (gr < NN) {
#pragma unroll
        for (int j = 0; j < 2; j++) {
          int gc = wc * 32 + j * 16 + (lane & 15);
          xlr2[(size_t)gr * 64 + gc] = acc[i][j][reg];
        }
      }
    }
  }
}

// ---------------- layer-1 scores + no-max softmax: wave per dst node ----------------
// lane owns channels lane*16..+15 (head = lane>>3). Reads only xl[s] per edge;
// xr[d], att in registers. w = exp(e) (|e| <~ 8, fp32-safe), den accumulated
// in-register -> den1. Eliminates the 3-pass softmax.
__global__ __launch_bounds__(256) void score1n(const int* __restrict__ rowptr, const int* __restrict__ csr_s,
                                               const short* __restrict__ xlr, const float* __restrict__ att,
                                               const float* __restrict__ alar,
                                               float* __restrict__ w1, float* __restrict__ den1) {
  const int lane = threadIdx.x & 63;
  const int d = blockIdx.x * 4 + (threadIdx.x >> 6);
  if (d >= NN) return;
  const int h = lane >> 3;
  const uint4* xrp = (const uint4*)(xlr + (size_t)d * 2048 + 1024 + lane * 16);
  uint4 rA = xrp[0], rB = xrp[1];
  float xr[16];
  xr[0] = b2f_lo(rA.x); xr[1] = b2f_hi(rA.x); xr[2] = b2f_lo(rA.y); xr[3] = b2f_hi(rA.y);
  xr[4] = b2f_lo(rA.z); xr[5] = b2f_hi(rA.z); xr[6] = b2f_lo(rA.w); xr[7] = b2f_hi(rA.w);
  xr[8] = b2f_lo(rB.x); xr[9] = b2f_hi(rB.x); xr[10] = b2f_lo(rB.y); xr[11] = b2f_hi(rB.y);
  xr[12] = b2f_lo(rB.z); xr[13] = b2f_hi(rB.z); xr[14] = b2f_lo(rB.w); xr[15] = b2f_hi(rB.w);
  const float4* a4 = (const float4*)(att + lane * 16);
  const float4 t0 = a4[0], t1 = a4[1], t2 = a4[2], t3 = a4[3];
  const float ar_h = alar[d * 16 + 8 + h];
  const int jb = rowptr[d], je = rowptr[d + 1];
  float den = 0.f;
#pragma unroll 2
  for (int j = jb; j < je; j++) {
    int s = csr_s[j];
    const uint4* xp = (const uint4*)(xlr + (size_t)s * 2048 + lane * 16);
    uint4 A = xp[0], B = xp[1];
    float p;
    p  = fabsf(b2f_lo(A.x) + xr[0]) * t0.x;
    p += fabsf(b2f_hi(A.x) + xr[1]) * t0.y;
    p += fabsf(b2f_lo(A.y) + xr[2]) * t0.z;
    p += fabsf(b2f_hi(A.y) + xr[3]) * t0.w;
    p += fabsf(b2f_lo(A.z) + xr[4]) * t1.x;
    p += fabsf(b2f_hi(A.z) + xr[5]) * t1.y;
    p += fabsf(b2f_lo(A.w) + xr[6]) * t1.z;
    p += fabsf(b2f_hi(A.w) + xr[7]) * t1.w;
    p += fabsf(b2f_lo(B.x) + xr[8]) * t2.x;
    p += fabsf(b2f_hi(B.x) + xr[9]) * t2.y;
    p += fabsf(b2f_lo(B.y) + xr[10]) * t2.z;
    p += fabsf(b2f_hi(B.y) + xr[11]) * t2.w;
    p += fabsf(b2f_lo(B.z) + xr[12]) * t3.x;
    p += fabsf(b2f_hi(B.z) + xr[13]) * t3.y;
    p += fabsf(b2f_lo(B.w) + xr[14]) * t3.z;
    p += fabsf(b2f_hi(B.w) + xr[15]) * t3.w;
    p += __shfl_xor(p, 1);
    p += __shfl_xor(p, 2);
    p += __shfl_xor(p, 4);
    float e = 0.4f * p + 0.6f * (alar[s * 16 + h] + ar_h);
    float w = __expf(e);
    den += w;
    if ((lane & 7) == 0) w1[j * 8 + h] = w;
  }
  if ((lane & 7) == 0) den1[d * 8 + h] = den;
}

// ---------------- layer-1 aggregation: 2 waves per dst; normalize at end ----------------
__global__ __launch_bounds__(256) void agg1_fast(const int* __restrict__ rowptr, const int* __restrict__ csr_s,
                                                 const float* __restrict__ w1, const float* __restrict__ den1,
                                                 const short* __restrict__ xlr,
                                                 const float* __restrict__ b1, short* __restrict__ h1b) {
  const int widx = threadIdx.x >> 6;
  const int lane = threadIdx.x & 63;
  const int d = blockIdx.x * 2 + (widx >> 1);
  const int ch = (widx & 1) * 512 + lane * 8;
  const int h = ch >> 7;
  const int jb = rowptr[d], je = rowptr[d + 1];
  float a0 = 0.f, a1 = 0.f, a2 = 0.f, a3 = 0.f, a4 = 0.f, a5 = 0.f, a6 = 0.f, a7 = 0.f;
#pragma unroll 4
  for (int j = jb; j < je; j++) {
    int s = csr_s[j];
    float al = w1[j * 8 + h];
    uint4 v = *(const uint4*)(xlr + (size_t)s * 2048 + ch);
    a0 += al * b2f_lo(v.x); a1 += al * b2f_hi(v.x);
    a2 += al * b2f_lo(v.y); a3 += al * b2f_hi(v.y);
    a4 += al * b2f_lo(v.z); a5 += al * b2f_hi(v.z);
    a6 += al * b2f_lo(v.w); a7 += al * b2f_hi(v.w);
  }
  const float inv = 1.f / (den1[d * 8 + h] + 1e-16f);
  const float4 b0 = *(const float4*)(b1 + ch);
  const float4 b4 = *(const float4*)(b1 + ch + 4);
  a0 = a0 * inv + b0.x; a1 = a1 * inv + b0.y; a2 = a2 * inv + b0.z; a3 = a3 * inv + b0.w;
  a4 = a4 * inv + b4.x; a5 = a5 * inv + b4.y; a6 = a6 * inv + b4.z; a7 = a7 * inv + b4.w;
  a0 = a0 > 0.f ? a0 : expm1f(a0);
  a1 = a1 > 0.f ? a1 : expm1f(a1);
  a2 = a2 > 0.f ? a2 : expm1f(a2);
  a3 = a3 > 0.f ? a3 : expm1f(a3);
  a4 = a4 > 0.f ? a4 : expm1f(a4);
  a5 = a5 > 0.f ? a5 : expm1f(a5);
  a6 = a6 > 0.f ? a6 : expm1f(a6);
  a7 = a7 > 0.f ? a7 : expm1f(a7);
  ushort4 o0, o4;
  o0.x = f2b(a0); o0.y = f2b(a1); o0.z = f2b(a2); o0.w = f2b(a3);
  o4.x = f2b(a4); o4.y = f2b(a5); o4.z = f2b(a6); o4.w = f2b(a7);
  *(ushort4*)(h1b + (size_t)d * 1024 + ch) = o0;
  *(ushort4*)(h1b + (size_t)d * 1024 + ch + 4) = o4;
}

// ---------------- layer-2 scores + no-max softmax: 32-lane group per dst ----------------
__global__ __launch_bounds__(256) void score2n(const int* __restrict__ rowptr, const int* __restrict__ csr_s,
                                               const float* __restrict__ xlr2, const float* __restrict__ att2,
                                               float* __restrict__ w2, float* __restrict__ den2) {
  const int t = threadIdx.x;
  const int d = blockIdx.x * 8 + (t >> 5);
  const int c = t & 31;
  if (d >= NN) return;
  const float xr = xlr2[d * 64 + 32 + c];
  const float a2 = att2[c];
  const int jb = rowptr[d], je = rowptr[d + 1];
  float den = 0.f;
#pragma unroll 2
  for (int j = jb; j < je; j++) {
    int s = csr_s[j];
    float p = a2 * lrelu(xlr2[s * 64 + c] + xr);
#pragma unroll
    for (int off = 16; off > 0; off >>= 1) p += __shfl_xor(p, off);
    float w = __expf(p);
    den += w;
    if (c == 0) w2[j] = w;
  }
  if (c == 0) den2[d] = den;
}

// ---------------- layer-2 aggregation + bias + log_softmax (32 lanes per dst) ----------------
__global__ __launch_bounds__(256) void agg2_fast(const int* __restrict__ rowptr, const int* __restrict__ csr_s,
                                                 const float* __restrict__ w2, const float* __restrict__ den2,
                                                 const float* __restrict__ xlr2,
                                                 const float* __restrict__ b2, float* __restrict__ out) {
  const int t = threadIdx.x;
  const int d = blockIdx.x * 8 + (t >> 5);
  const int c = t & 31;
  if (d >= NN) return;
  const int jb = rowptr[d], je = rowptr[d + 1];
  float acc = 0.f;
#pragma unroll 4
  for (int j = jb; j < je; j++) {
    acc += w2[j] * xlr2[csr_s[j] * 64 + c];
  }
  const float inv = 1.f / (den2[d] + 1e-16f);
  float v = acc * inv + b2[c];
  float mx = v;
#pragma unroll
  for (int off = 16; off > 0; off >>= 1) mx = fmaxf(mx, __shfl_xor(mx, off));
  float ex = __expf(v - mx);
  float sum = ex;
#pragma unroll
  for (int off = 16; off > 0; off >>= 1) sum += __shfl_xor(sum, off);
  out[d * 32 + c] = v - mx - logf(sum);
}

extern "C" void kernel_launch(void* const* d_in, const int* in_sizes, int n_in,
                              void* d_out, int out_size, void* d_ws, size_t ws_size,
                              hipStream_t stream) {
  const float* x    = (const float*)d_in[0];
  const int*   ei   = (const int*)d_in[1];
  const float* W1l  = (const float*)d_in[2];
  const float* W1r  = (const float*)d_in[3];
  const float* att1 = (const float*)d_in[4];
  const float* b1   = (const float*)d_in[5];
  const float* W2l  = (const float*)d_in[6];
  const float* W2r  = (const float*)d_in[7];
  const float* att2 = (const float*)d_in[8];
  const float* b2   = (const float*)d_in[9];
  float* out = (float*)d_out;

  // workspace layout
  short* Xb   = (short*)d_ws;                        // MPAD*256
  short* Wt1  = Xb + (size_t)MPAD * 256;             // 2048*256
  short* Wt2  = Wt1 + (size_t)2048 * 256;            // 64*1024
  short* xlr  = Wt2 + (size_t)64 * 1024;             // NN*2048 bf16 (xl | xr)
  short* h1b  = xlr + (size_t)NN * 2048;             // MPAD*1024 bf16
  float* xlr2 = (float*)(h1b + (size_t)MPAD * 1024); // NN*64
  float* alar = xlr2 + (size_t)NN * 64;              // NN*16
  float* w1   = alar + (size_t)NN * 16;              // NE*8 (exp weights)
  float* den1 = w1 + (size_t)NE * 8;                 // NN*8
  float* w2   = den1 + (size_t)NN * 8;               // NE
  float* den2 = w2 + NE;                             // NN
  int* deg    = (int*)(den2 + NN);                   // NN
  int* rowptr = deg + NN;                            // NN+1
  int* cursor = rowptr + NN + 1;                     // NN
  int* csr_s  = cursor + NN;                         // NE

  const int* src = ei;
  const int* dst = ei + NE;

  // CSR build + conversions (fused prep)
  hipMemsetAsync(deg, 0, NN * sizeof(int), stream);
  prep<<<NB_CVT + NB_W1 + NB_W2 + NB_DEG, 256, 0, stream>>>(x, Xb, W1l, W1r, Wt1,
                                                            W2l, W2r, Wt2, dst, deg);
  scan_rowptr<<<1, 1024, 0, stream>>>(deg, rowptr, cursor);
  csr_fill<<<(NE + 255) / 256, 256, 0, stream>>>(src, dst, cursor, csr_s);

  // layer-1 GEMM -> xlr bf16 [NN][2048] + alar (fused)
  {
    dim3 g(16, 79);
    gemm1_fused<<<g, 256, 0, stream>>>(Xb, Wt1, att1, xlr, alar);
  }

  // layer-1 attention
  score1n<<<(NN + 3) / 4, 256, 0, stream>>>(rowptr, csr_s, xlr, att1, alar, w1, den1);
  agg1_fast<<<NN / 2, 256, 0, stream>>>(rowptr, csr_s, w1, den1, xlr, b1, h1b);

  // layer-2 GEMM -> xlr2 fp32 [NN][64]
  {
    dim3 g(1, MPAD / 64);
    gemm2_64<<<g, 256, 0, stream>>>(h1b, Wt2, xlr2);
  }

  // layer-2 attention
  score2n<<<(NN + 7) / 8, 256, 0, stream>>>(rowptr, csr_s, xlr2, att2, w2, den2);
  agg2_fast<<<(NN + 7) / 8, 256, 0, stream>>>(rowptr, csr_s, w2, den2, xlr2, b2, out);
}

// Round 11
// 259.032 us; speedup vs baseline: 1.6456x; 1.1559x over previous
//
#include <hip/hip_runtime.h>
#include <hip/hip_bf16.h>

constexpr int NN   = 10000;
constexpr int NE   = 160000;
constexpr int INC  = 256;
constexpr int H    = 8;
constexpr int D1   = 1024;     // 8 heads x 128
constexpr int OUTC = 32;
constexpr int MPAD = 10112;    // 79 * 128
constexpr float NEG_SLOPE = 0.2f;

typedef __attribute__((ext_vector_type(8))) short bf16x8;
typedef __attribute__((ext_vector_type(4))) float f32x4;

__device__ __forceinline__ unsigned short f2b(float f) {
  unsigned u = __float_as_uint(f);
  unsigned r = (u + 0x7fffu + ((u >> 16) & 1u)) >> 16;
  return (unsigned short)r;
}
__device__ __forceinline__ float b2f_lo(unsigned u) { return __uint_as_float(u << 16); }
__device__ __forceinline__ float b2f_hi(unsigned u) { return __uint_as_float(u & 0xffff0000u); }
__device__ __forceinline__ float lrelu(float a) { return fmaxf(a, 0.f) + NEG_SLOPE * fminf(a, 0.f); }

// ---------------- uber prep: x->bf16 pad, W1 transpose, W2 transpose, deg hist ----------------
constexpr int NB_CVT = MPAD * INC / 4 / 256;        // 2528
constexpr int NB_W1X = 2048 / 32;                   // 64
constexpr int NB_W1  = NB_W1X * (256 / 32);         // 512
constexpr int NB_W2X = 64 / 32;                     // 2
constexpr int NB_W2  = NB_W2X * (1024 / 32);        // 64
constexpr int NB_DEG = (NE + 255) / 256;            // 625

__device__ __forceinline__ void transpose_body(const float* __restrict__ srcA,
                                               const float* __restrict__ srcB,
                                               short* __restrict__ dst,
                                               int K, int NsrcHalf, int bx, int by,
                                               int tx, int ty) {
  __shared__ float tile[32][33];
  int nb = bx * 32, kb = by * 32;
  const float* src = srcA;
  int nloc = nb;
  if (nb >= NsrcHalf) { src = srcB; nloc = nb - NsrcHalf; }
#pragma unroll
  for (int i = 0; i < 4; i++)
    tile[ty + i * 8][tx] = src[(size_t)(kb + ty + i * 8) * NsrcHalf + nloc + tx];
  __syncthreads();
#pragma unroll
  for (int i = 0; i < 4; i++)
    dst[(size_t)(nb + ty + i * 8) * K + kb + tx] = (short)f2b(tile[tx][ty + i * 8]);
}

__global__ __launch_bounds__(256) void prep(const float* __restrict__ x, short* __restrict__ Xb,
                                            const float* __restrict__ W1l, const float* __restrict__ W1r,
                                            short* __restrict__ Wt1,
                                            const float* __restrict__ W2l, const float* __restrict__ W2r,
                                            short* __restrict__ Wt2,
                                            const int* __restrict__ dst, int* __restrict__ deg) {
  const int b = blockIdx.x;
  const int t = threadIdx.x;
  if (b < NB_CVT) {
    int base = (b * 256 + t) * 4;
    ushort4 o;
    if (base < NN * INC) {
      float4 v = *(const float4*)(x + base);
      o.x = f2b(v.x); o.y = f2b(v.y); o.z = f2b(v.z); o.w = f2b(v.w);
    } else {
      o.x = o.y = o.z = o.w = 0;
    }
    *(ushort4*)(Xb + base) = o;
  } else if (b < NB_CVT + NB_W1) {
    int bb = b - NB_CVT;
    transpose_body(W1l, W1r, Wt1, 256, 1024, bb % NB_W1X, bb / NB_W1X, t & 31, t >> 5);
  } else if (b < NB_CVT + NB_W1 + NB_W2) {
    int bb = b - NB_CVT - NB_W1;
    transpose_body(W2l, W2r, Wt2, 1024, 32, bb % NB_W2X, bb / NB_W2X, t & 31, t >> 5);
  } else {
    int e = (b - NB_CVT - NB_W1 - NB_W2) * 256 + t;
    if (e < NE) atomicAdd(&deg[dst[e]], 1);
  }
}

// ---------------- parallel exclusive scan: 1 block x 1024 threads ----------------
__global__ __launch_bounds__(1024) void scan_rowptr(const int* __restrict__ deg,
                                                    int* __restrict__ rowptr,
                                                    int* __restrict__ cursor) {
  __shared__ int wsum[16];
  const int t = threadIdx.x;
  const int lane = t & 63, w = t >> 6;
  const int base = t * 10;
  int v[10];
  int tot = 0;
#pragma unroll
  for (int i = 0; i < 10; i++) {
    int idx = base + i;
    int x = (idx < NN) ? deg[idx] : 0;
    v[i] = tot;
    tot += x;
  }
  int ws = tot;
#pragma unroll
  for (int off = 1; off < 64; off <<= 1) {
    int u = __shfl_up(ws, off);
    if (lane >= off) ws += u;
  }
  if (lane == 63) wsum[w] = ws;
  __syncthreads();
  if (w == 0) {
    int x = (lane < 16) ? wsum[lane] : 0;
#pragma unroll
    for (int off = 1; off < 16; off <<= 1) {
      int u = __shfl_up(x, off);
      if (lane >= off) x += u;
    }
    if (lane < 16) wsum[lane] = x;
  }
  __syncthreads();
  const int wbase = (w > 0) ? wsum[w - 1] : 0;
  const int tbase = wbase + ws - tot;
#pragma unroll
  for (int i = 0; i < 10; i++) {
    int idx = base + i;
    if (idx < NN) {
      int r = tbase + v[i];
      rowptr[idx] = r;
      cursor[idx] = r;
    }
  }
  if (t == 1023) rowptr[NN] = wbase + ws;
}

__global__ void csr_fill(const int* __restrict__ src, const int* __restrict__ dst,
                         int* __restrict__ cursor, int* __restrict__ csr_s) {
  int e = blockIdx.x * 256 + threadIdx.x;
  if (e >= NE) return;
  int pos = atomicAdd(&cursor[dst[e]], 1);
  csr_s[pos] = src[e];
}

// ---------------- layer-1 GEMM, fused epilogue (coalesced bf16 store + alar dots) ----------------
__global__ __launch_bounds__(256) void gemm1_fused(const short* __restrict__ Xb,
                                                   const short* __restrict__ Wt,
                                                   const float* __restrict__ att,
                                                   short* __restrict__ xlr,
                                                   float* __restrict__ alar) {
  __shared__ short As[4096];
  __shared__ short Bs[4096];
  __shared__ short Cs[128][136];
  const int t = threadIdx.x;
  const int lane = t & 63;
  const int w = t >> 6;
  const int wr = w >> 1, wc = w & 1;
  const int row0 = blockIdx.y * 128;
  const int col0 = blockIdx.x * 128;
  const int r_st = t & 127;
  const int kc_st = t >> 7;
  f32x4 acc[4][4] = {};
  for (int k0 = 0; k0 < 256; k0 += 32) {
    bf16x8 va0 = *(const bf16x8*)(Xb + (size_t)(row0 + r_st) * 256 + k0 + kc_st * 8);
    bf16x8 va1 = *(const bf16x8*)(Xb + (size_t)(row0 + r_st) * 256 + k0 + (kc_st + 2) * 8);
    bf16x8 vb0 = *(const bf16x8*)(Wt + (size_t)(col0 + r_st) * 256 + k0 + kc_st * 8);
    bf16x8 vb1 = *(const bf16x8*)(Wt + (size_t)(col0 + r_st) * 256 + k0 + (kc_st + 2) * 8);
    __syncthreads();
    *(bf16x8*)&As[(kc_st)     * 1024 + r_st * 8] = va0;
    *(bf16x8*)&As[(kc_st + 2) * 1024 + r_st * 8] = va1;
    *(bf16x8*)&Bs[(kc_st)     * 1024 + r_st * 8] = vb0;
    *(bf16x8*)&Bs[(kc_st + 2) * 1024 + r_st * 8] = vb1;
    __syncthreads();
    bf16x8 af[4], bfr[4];
#pragma unroll
    for (int i = 0; i < 4; i++)
      af[i] = *(const bf16x8*)&As[(lane >> 4) * 1024 + (wr * 64 + i * 16 + (lane & 15)) * 8];
#pragma unroll
    for (int j = 0; j < 4; j++)
      bfr[j] = *(const bf16x8*)&Bs[(lane >> 4) * 1024 + (wc * 64 + j * 16 + (lane & 15)) * 8];
#pragma unroll
    for (int i = 0; i < 4; i++)
#pragma unroll
      for (int j = 0; j < 4; j++)
        acc[i][j] = __builtin_amdgcn_mfma_f32_16x16x32_bf16(af[i], bfr[j], acc[i][j], 0, 0, 0);
  }
  __syncthreads();
#pragma unroll
  for (int i = 0; i < 4; i++) {
#pragma unroll
    for (int reg = 0; reg < 4; reg++) {
      int r = wr * 64 + i * 16 + (lane >> 4) * 4 + reg;
#pragma unroll
      for (int j = 0; j < 4; j++)
        Cs[r][wc * 64 + j * 16 + (lane & 15)] = (short)f2b(acc[i][j][reg]);
    }
  }
  __syncthreads();
  const int r = t >> 1, half = t & 1;
  const int gr = row0 + r;
  float dot = 0.f;
  if (gr < NN) {
#pragma unroll
    for (int chunk = 0; chunk < 8; chunk++) {
      const int cloc = half * 64 + chunk * 8;
      uint4 v = *(const uint4*)&Cs[r][cloc];
      *(uint4*)(xlr + (size_t)gr * 2048 + col0 + cloc) = v;
      const int ca = (col0 + cloc) & 1023;
      const float4 a0 = *(const float4*)(att + ca);
      const float4 a1 = *(const float4*)(att + ca + 4);
      dot += b2f_lo(v.x) * a0.x + b2f_hi(v.x) * a0.y
           + b2f_lo(v.y) * a0.z + b2f_hi(v.y) * a0.w
           + b2f_lo(v.z) * a1.x + b2f_hi(v.z) * a1.y
           + b2f_lo(v.w) * a1.z + b2f_hi(v.w) * a1.w;
    }
  }
  dot += __shfl_xor(dot, 1);
  if (half == 0 && gr < NN) alar[gr * 16 + blockIdx.x] = dot;
}

// ---------------- layer-2 GEMM: [MPAD x 1024] x [64 x 1024]^T -> fp32 [NN][64] ----------------
__global__ __launch_bounds__(256) void gemm2_64(const short* __restrict__ h1b,
                                                const short* __restrict__ Wt2,
                                                float* __restrict__ xlr2) {
  __shared__ short As[4][64][8];
  __shared__ short Bs[4][64][8];
  const int t = threadIdx.x;
  const int lane = t & 63;
  const int wv = t >> 6;
  const int wr = wv >> 1, wc = wv & 1;
  const int row0 = blockIdx.y * 64;
  const int r_st = t & 63;
  const int kc2 = t >> 6;
  f32x4 acc[2][2] = {};
  for (int k0 = 0; k0 < 1024; k0 += 32) {
    bf16x8 va = *(const bf16x8*)(h1b + (size_t)(row0 + r_st) * 1024 + k0 + kc2 * 8);
    bf16x8 vb = *(const bf16x8*)(Wt2 + (size_t)r_st * 1024 + k0 + kc2 * 8);
    __syncthreads();
    *(bf16x8*)&As[kc2][r_st][0] = va;
    *(bf16x8*)&Bs[kc2][r_st][0] = vb;
    __syncthreads();
    const int ks = lane >> 4;
    bf16x8 af0 = *(const bf16x8*)&As[ks][wr * 32 + (lane & 15)][0];
    bf16x8 af1 = *(const bf16x8*)&As[ks][wr * 32 + 16 + (lane & 15)][0];
    bf16x8 bf0 = *(const bf16x8*)&Bs[ks][wc * 32 + (lane & 15)][0];
    bf16x8 bf1 = *(const bf16x8*)&Bs[ks][wc * 32 + 16 + (lane & 15)][0];
    acc[0][0] = __builtin_amdgcn_mfma_f32_16x16x32_bf16(af0, bf0, acc[0][0], 0, 0, 0);
    acc[0][1] = __builtin_amdgcn_mfma_f32_16x16x32_bf16(af0, bf1, acc[0][1], 0, 0, 0);
    acc[1][0] = __builtin_amdgcn_mfma_f32_16x16x32_bf16(af1, bf0, acc[1][0], 0, 0, 0);
    acc[1][1] = __builtin_amdgcn_mfma_f32_16x16x32_bf16(af1, bf1, acc[1][1], 0, 0, 0);
  }
#pragma unroll
  for (int i = 0; i < 2; i++) {
#pragma unroll
    for (int reg = 0; reg < 4; reg++) {
      int gr = row0 + wr * 32 + i * 16 + (lane >> 4) * 4 + reg;
      if (gr < NN) {
#pragma unroll
        for (int j = 0; j < 2; j++) {
          int gc = wc * 32 + j * 16 + (lane & 15);
          xlr2[(size_t)gr * 64 + gc] = acc[i][j][reg];
        }
      }
    }
  }
}

// ---------------- fused layer-1: score + ONLINE softmax + agg + bias + ELU ----------------
// agg1_fast skeleton (proven): 2 waves per dst, lane owns 8 channels as named
// scalars (no register arrays). Score: 16-lane butterfly per head group; one
// xl[s] read per edge feeds score AND accumulation. Online rescale (R4-proven).
__global__ __launch_bounds__(256) void fused1(const int* __restrict__ rowptr, const int* __restrict__ csr_s,
                                              const short* __restrict__ xlr, const float* __restrict__ att,
                                              const float* __restrict__ alar,
                                              const float* __restrict__ b1, short* __restrict__ h1b) {
  const int widx = threadIdx.x >> 6;
  const int lane = threadIdx.x & 63;
  const int d = blockIdx.x * 2 + (widx >> 1);
  const int ch = (widx & 1) * 512 + lane * 8;   // 8 channels; lanes 0-15 = one head
  const int h = ch >> 7;
  const uint4 rv = *(const uint4*)(xlr + (size_t)d * 2048 + 1024 + ch);
  const float xr0 = b2f_lo(rv.x), xr1 = b2f_hi(rv.x);
  const float xr2 = b2f_lo(rv.y), xr3 = b2f_hi(rv.y);
  const float xr4 = b2f_lo(rv.z), xr5 = b2f_hi(rv.z);
  const float xr6 = b2f_lo(rv.w), xr7 = b2f_hi(rv.w);
  const float4 ta = *(const float4*)(att + ch);
  const float4 tb = *(const float4*)(att + ch + 4);
  const float ar_h = alar[d * 16 + 8 + h];
  const int jb = rowptr[d], je = rowptr[d + 1];
  float m = -3.4e38f, den = 0.f;
  float c0 = 0.f, c1 = 0.f, c2 = 0.f, c3 = 0.f, c4 = 0.f, c5 = 0.f, c6 = 0.f, c7 = 0.f;
  for (int j = jb; j < je; j++) {
    const int s = csr_s[j];
    const uint4 v = *(const uint4*)(xlr + (size_t)s * 2048 + ch);
    const float x0 = b2f_lo(v.x), x1 = b2f_hi(v.x);
    const float x2 = b2f_lo(v.y), x3 = b2f_hi(v.y);
    const float x4 = b2f_lo(v.z), x5 = b2f_hi(v.z);
    const float x6 = b2f_lo(v.w), x7 = b2f_hi(v.w);
    float p = fabsf(x0 + xr0) * ta.x;
    p += fabsf(x1 + xr1) * ta.y;
    p += fabsf(x2 + xr2) * ta.z;
    p += fabsf(x3 + xr3) * ta.w;
    p += fabsf(x4 + xr4) * tb.x;
    p += fabsf(x5 + xr5) * tb.y;
    p += fabsf(x6 + xr6) * tb.z;
    p += fabsf(x7 + xr7) * tb.w;
    p += __shfl_xor(p, 1);
    p += __shfl_xor(p, 2);
    p += __shfl_xor(p, 4);
    p += __shfl_xor(p, 8);      // sum over the 16 lanes of this head
    const float e = 0.4f * p + 0.6f * (alar[s * 16 + h] + ar_h);
    if (e > m) {                 // uniform across the 16-lane head group
      const float r = __expf(m - e);   // 0 on first edge
      c0 *= r; c1 *= r; c2 *= r; c3 *= r;
      c4 *= r; c5 *= r; c6 *= r; c7 *= r;
      den *= r;
      m = e;
    }
    const float w = __expf(e - m);
    den += w;
    c0 += w * x0; c1 += w * x1; c2 += w * x2; c3 += w * x3;
    c4 += w * x4; c5 += w * x5; c6 += w * x6; c7 += w * x7;
  }
  const float inv = 1.f / (den + 1e-16f);
  const float4 b0 = *(const float4*)(b1 + ch);
  const float4 b4 = *(const float4*)(b1 + ch + 4);
  c0 = c0 * inv + b0.x; c1 = c1 * inv + b0.y; c2 = c2 * inv + b0.z; c3 = c3 * inv + b0.w;
  c4 = c4 * inv + b4.x; c5 = c5 * inv + b4.y; c6 = c6 * inv + b4.z; c7 = c7 * inv + b4.w;
  c0 = c0 > 0.f ? c0 : expm1f(c0);
  c1 = c1 > 0.f ? c1 : expm1f(c1);
  c2 = c2 > 0.f ? c2 : expm1f(c2);
  c3 = c3 > 0.f ? c3 : expm1f(c3);
  c4 = c4 > 0.f ? c4 : expm1f(c4);
  c5 = c5 > 0.f ? c5 : expm1f(c5);
  c6 = c6 > 0.f ? c6 : expm1f(c6);
  c7 = c7 > 0.f ? c7 : expm1f(c7);
  uint4 o;
  o.x = (unsigned)f2b(c0) | ((unsigned)f2b(c1) << 16);
  o.y = (unsigned)f2b(c2) | ((unsigned)f2b(c3) << 16);
  o.z = (unsigned)f2b(c4) | ((unsigned)f2b(c5) << 16);
  o.w = (unsigned)f2b(c6) | ((unsigned)f2b(c7) << 16);
  *(uint4*)(h1b + (size_t)d * 1024 + ch) = o;
}

// ---------------- fused layer-2: score + ONLINE softmax + agg + bias + log_softmax ----------------
// R4-proven attn2 pattern (32-lane group per dst, online rescale) + fused logsm.
__global__ __launch_bounds__(256) void fused2(const int* __restrict__ rowptr, const int* __restrict__ csr_s,
                                              const float* __restrict__ xlr2, const float* __restrict__ att2,
                                              const float* __restrict__ b2, float* __restrict__ out) {
  const int t = threadIdx.x;
  const int d = blockIdx.x * 8 + (t >> 5);
  const int c = t & 31;
  if (d >= NN) return;
  const float xr = xlr2[d * 64 + 32 + c];
  const float a2 = att2[c];
  const int jb = rowptr[d], je = rowptr[d + 1];
  float m = -3.4e38f, den = 0.f, acc = 0.f;
  for (int j = jb; j < je; j++) {
    const int s = csr_s[j];
    const float xv = xlr2[s * 64 + c];
    float p = a2 * lrelu(xv + xr);
#pragma unroll
    for (int off = 16; off > 0; off >>= 1) p += __shfl_xor(p, off);
    if (p > m) {
      const float r = __expf(m - p);
      acc *= r; den *= r; m = p;
    }
    const float w = __expf(p - m);
    den += w;
    acc += w * xv;
  }
  float v = acc / (den + 1e-16f) + b2[c];
  float mx = v;
#pragma unroll
  for (int off = 16; off > 0; off >>= 1) mx = fmaxf(mx, __shfl_xor(mx, off));
  float ex = __expf(v - mx);
  float sum = ex;
#pragma unroll
  for (int off = 16; off > 0; off >>= 1) sum += __shfl_xor(sum, off);
  out[d * 32 + c] = v - mx - logf(sum);
}

extern "C" void kernel_launch(void* const* d_in, const int* in_sizes, int n_in,
                              void* d_out, int out_size, void* d_ws, size_t ws_size,
                              hipStream_t stream) {
  const float* x    = (const float*)d_in[0];
  const int*   ei   = (const int*)d_in[1];
  const float* W1l  = (const float*)d_in[2];
  const float* W1r  = (const float*)d_in[3];
  const float* att1 = (const float*)d_in[4];
  const float* b1   = (const float*)d_in[5];
  const float* W2l  = (const float*)d_in[6];
  const float* W2r  = (const float*)d_in[7];
  const float* att2 = (const float*)d_in[8];
  const float* b2   = (const float*)d_in[9];
  float* out = (float*)d_out;

  // workspace layout
  short* Xb   = (short*)d_ws;                        // MPAD*256
  short* Wt1  = Xb + (size_t)MPAD * 256;             // 2048*256
  short* Wt2  = Wt1 + (size_t)2048 * 256;            // 64*1024
  short* xlr  = Wt2 + (size_t)64 * 1024;             // NN*2048 bf16 (xl | xr)
  short* h1b  = xlr + (size_t)NN * 2048;             // MPAD*1024 bf16
  float* xlr2 = (float*)(h1b + (size_t)MPAD * 1024); // NN*64
  float* alar = xlr2 + (size_t)NN * 64;              // NN*16
  int* deg    = (int*)(alar + (size_t)NN * 16);      // NN
  int* rowptr = deg + NN;                            // NN+1
  int* cursor = rowptr + NN + 1;                     // NN
  int* csr_s  = cursor + NN;                         // NE

  const int* src = ei;
  const int* dst = ei + NE;

  // CSR build + conversions (fused prep)
  hipMemsetAsync(deg, 0, NN * sizeof(int), stream);
  prep<<<NB_CVT + NB_W1 + NB_W2 + NB_DEG, 256, 0, stream>>>(x, Xb, W1l, W1r, Wt1,
                                                            W2l, W2r, Wt2, dst, deg);
  scan_rowptr<<<1, 1024, 0, stream>>>(deg, rowptr, cursor);
  csr_fill<<<(NE + 255) / 256, 256, 0, stream>>>(src, dst, cursor, csr_s);

  // layer-1 GEMM -> xlr bf16 [NN][2048] + alar (fused)
  {
    dim3 g(16, 79);
    gemm1_fused<<<g, 256, 0, stream>>>(Xb, Wt1, att1, xlr, alar);
  }

  // fused layer-1 attention (single pass over edges, 2 waves per dst)
  fused1<<<NN / 2, 256, 0, stream>>>(rowptr, csr_s, xlr, att1, alar, b1, h1b);

  // layer-2 GEMM -> xlr2 fp32 [NN][64]
  {
    dim3 g(1, MPAD / 64);
    gemm2_64<<<g, 256, 0, stream>>>(h1b, Wt2, xlr2);
  }

  // fused layer-2 attention + log_softmax
  fused2<<<(NN + 7) / 8, 256, 0, stream>>>(rowptr, csr_s, xlr2, att2, b2, out);
}

// Round 12
// 252.882 us; speedup vs baseline: 1.6856x; 1.0243x over previous
//
#include <hip/hip_runtime.h>
#include <hip/hip_bf16.h>

constexpr int NN   = 10000;
constexpr int NE   = 160000;
constexpr int INC  = 256;
constexpr int H    = 8;
constexpr int D1   = 1024;     // 8 heads x 128
constexpr int OUTC = 32;
constexpr int MPAD = 10112;    // 79 * 128
constexpr float NEG_SLOPE = 0.2f;

typedef __attribute__((ext_vector_type(8))) short bf16x8;
typedef __attribute__((ext_vector_type(4))) float f32x4;

__device__ __forceinline__ unsigned short f2b(float f) {
  unsigned u = __float_as_uint(f);
  unsigned r = (u + 0x7fffu + ((u >> 16) & 1u)) >> 16;
  return (unsigned short)r;
}
__device__ __forceinline__ float b2f_lo(unsigned u) { return __uint_as_float(u << 16); }
__device__ __forceinline__ float b2f_hi(unsigned u) { return __uint_as_float(u & 0xffff0000u); }
__device__ __forceinline__ float lrelu(float a) { return fmaxf(a, 0.f) + NEG_SLOPE * fminf(a, 0.f); }

// ---------------- uber prep: x->bf16 pad, W1 transpose, W2 transpose, deg hist ----------------
constexpr int NB_CVT = MPAD * INC / 4 / 256;        // 2528
constexpr int NB_W1X = 2048 / 32;                   // 64
constexpr int NB_W1  = NB_W1X * (256 / 32);         // 512
constexpr int NB_W2X = 64 / 32;                     // 2
constexpr int NB_W2  = NB_W2X * (1024 / 32);        // 64
constexpr int NB_DEG = (NE + 255) / 256;            // 625

__device__ __forceinline__ void transpose_body(const float* __restrict__ srcA,
                                               const float* __restrict__ srcB,
                                               short* __restrict__ dst,
                                               int K, int NsrcHalf, int bx, int by,
                                               int tx, int ty) {
  __shared__ float tile[32][33];
  int nb = bx * 32, kb = by * 32;
  const float* src = srcA;
  int nloc = nb;
  if (nb >= NsrcHalf) { src = srcB; nloc = nb - NsrcHalf; }
#pragma unroll
  for (int i = 0; i < 4; i++)
    tile[ty + i * 8][tx] = src[(size_t)(kb + ty + i * 8) * NsrcHalf + nloc + tx];
  __syncthreads();
#pragma unroll
  for (int i = 0; i < 4; i++)
    dst[(size_t)(nb + ty + i * 8) * K + kb + tx] = (short)f2b(tile[tx][ty + i * 8]);
}

__global__ __launch_bounds__(256) void prep(const float* __restrict__ x, short* __restrict__ Xb,
                                            const float* __restrict__ W1l, const float* __restrict__ W1r,
                                            short* __restrict__ Wt1,
                                            const float* __restrict__ W2l, const float* __restrict__ W2r,
                                            short* __restrict__ Wt2,
                                            const int* __restrict__ dst, int* __restrict__ deg) {
  const int b = blockIdx.x;
  const int t = threadIdx.x;
  if (b < NB_CVT) {
    int base = (b * 256 + t) * 4;
    ushort4 o;
    if (base < NN * INC) {
      float4 v = *(const float4*)(x + base);
      o.x = f2b(v.x); o.y = f2b(v.y); o.z = f2b(v.z); o.w = f2b(v.w);
    } else {
      o.x = o.y = o.z = o.w = 0;
    }
    *(ushort4*)(Xb + base) = o;
  } else if (b < NB_CVT + NB_W1) {
    int bb = b - NB_CVT;
    transpose_body(W1l, W1r, Wt1, 256, 1024, bb % NB_W1X, bb / NB_W1X, t & 31, t >> 5);
  } else if (b < NB_CVT + NB_W1 + NB_W2) {
    int bb = b - NB_CVT - NB_W1;
    transpose_body(W2l, W2r, Wt2, 1024, 32, bb % NB_W2X, bb / NB_W2X, t & 31, t >> 5);
  } else {
    int e = (b - NB_CVT - NB_W1 - NB_W2) * 256 + t;
    if (e < NE) atomicAdd(&deg[dst[e]], 1);
  }
}

// ---------------- parallel exclusive scan: 1 block x 1024 threads ----------------
__global__ __launch_bounds__(1024) void scan_rowptr(const int* __restrict__ deg,
                                                    int* __restrict__ rowptr,
                                                    int* __restrict__ cursor) {
  __shared__ int wsum[16];
  const int t = threadIdx.x;
  const int lane = t & 63, w = t >> 6;
  const int base = t * 10;
  int v[10];
  int tot = 0;
#pragma unroll
  for (int i = 0; i < 10; i++) {
    int idx = base + i;
    int x = (idx < NN) ? deg[idx] : 0;
    v[i] = tot;
    tot += x;
  }
  int ws = tot;
#pragma unroll
  for (int off = 1; off < 64; off <<= 1) {
    int u = __shfl_up(ws, off);
    if (lane >= off) ws += u;
  }
  if (lane == 63) wsum[w] = ws;
  __syncthreads();
  if (w == 0) {
    int x = (lane < 16) ? wsum[lane] : 0;
#pragma unroll
    for (int off = 1; off < 16; off <<= 1) {
      int u = __shfl_up(x, off);
      if (lane >= off) x += u;
    }
    if (lane < 16) wsum[lane] = x;
  }
  __syncthreads();
  const int wbase = (w > 0) ? wsum[w - 1] : 0;
  const int tbase = wbase + ws - tot;
#pragma unroll
  for (int i = 0; i < 10; i++) {
    int idx = base + i;
    if (idx < NN) {
      int r = tbase + v[i];
      rowptr[idx] = r;
      cursor[idx] = r;
    }
  }
  if (t == 1023) rowptr[NN] = wbase + ws;
}

__global__ void csr_fill(const int* __restrict__ src, const int* __restrict__ dst,
                         int* __restrict__ cursor, int* __restrict__ csr_s) {
  int e = blockIdx.x * 256 + threadIdx.x;
  if (e >= NE) return;
  int pos = atomicAdd(&cursor[dst[e]], 1);
  csr_s[pos] = src[e];
}

// ---------------- layer-1 GEMM, fused epilogue (coalesced bf16 store + alar dots) ----------------
__global__ __launch_bounds__(256) void gemm1_fused(const short* __restrict__ Xb,
                                                   const short* __restrict__ Wt,
                                                   const float* __restrict__ att,
                                                   short* __restrict__ xlr,
                                                   float* __restrict__ alar) {
  __shared__ short As[4096];
  __shared__ short Bs[4096];
  __shared__ short Cs[128][136];
  const int t = threadIdx.x;
  const int lane = t & 63;
  const int w = t >> 6;
  const int wr = w >> 1, wc = w & 1;
  const int row0 = blockIdx.y * 128;
  const int col0 = blockIdx.x * 128;
  const int r_st = t & 127;
  const int kc_st = t >> 7;
  f32x4 acc[4][4] = {};
  for (int k0 = 0; k0 < 256; k0 += 32) {
    bf16x8 va0 = *(const bf16x8*)(Xb + (size_t)(row0 + r_st) * 256 + k0 + kc_st * 8);
    bf16x8 va1 = *(const bf16x8*)(Xb + (size_t)(row0 + r_st) * 256 + k0 + (kc_st + 2) * 8);
    bf16x8 vb0 = *(const bf16x8*)(Wt + (size_t)(col0 + r_st) * 256 + k0 + kc_st * 8);
    bf16x8 vb1 = *(const bf16x8*)(Wt + (size_t)(col0 + r_st) * 256 + k0 + (kc_st + 2) * 8);
    __syncthreads();
    *(bf16x8*)&As[(kc_st)     * 1024 + r_st * 8] = va0;
    *(bf16x8*)&As[(kc_st + 2) * 1024 + r_st * 8] = va1;
    *(bf16x8*)&Bs[(kc_st)     * 1024 + r_st * 8] = vb0;
    *(bf16x8*)&Bs[(kc_st + 2) * 1024 + r_st * 8] = vb1;
    __syncthreads();
    bf16x8 af[4], bfr[4];
#pragma unroll
    for (int i = 0; i < 4; i++)
      af[i] = *(const bf16x8*)&As[(lane >> 4) * 1024 + (wr * 64 + i * 16 + (lane & 15)) * 8];
#pragma unroll
    for (int j = 0; j < 4; j++)
      bfr[j] = *(const bf16x8*)&Bs[(lane >> 4) * 1024 + (wc * 64 + j * 16 + (lane & 15)) * 8];
#pragma unroll
    for (int i = 0; i < 4; i++)
#pragma unroll
      for (int j = 0; j < 4; j++)
        acc[i][j] = __builtin_amdgcn_mfma_f32_16x16x32_bf16(af[i], bfr[j], acc[i][j], 0, 0, 0);
  }
  __syncthreads();
#pragma unroll
  for (int i = 0; i < 4; i++) {
#pragma unroll
    for (int reg = 0; reg < 4; reg++) {
      int r = wr * 64 + i * 16 + (lane >> 4) * 4 + reg;
#pragma unroll
      for (int j = 0; j < 4; j++)
        Cs[r][wc * 64 + j * 16 + (lane & 15)] = (short)f2b(acc[i][j][reg]);
    }
  }
  __syncthreads();
  const int r = t >> 1, half = t & 1;
  const int gr = row0 + r;
  float dot = 0.f;
  if (gr < NN) {
#pragma unroll
    for (int chunk = 0; chunk < 8; chunk++) {
      const int cloc = half * 64 + chunk * 8;
      uint4 v = *(const uint4*)&Cs[r][cloc];
      *(uint4*)(xlr + (size_t)gr * 2048 + col0 + cloc) = v;
      const int ca = (col0 + cloc) & 1023;
      const float4 a0 = *(const float4*)(att + ca);
      const float4 a1 = *(const float4*)(att + ca + 4);
      dot += b2f_lo(v.x) * a0.x + b2f_hi(v.x) * a0.y
           + b2f_lo(v.y) * a0.z + b2f_hi(v.y) * a0.w
           + b2f_lo(v.z) * a1.x + b2f_hi(v.z) * a1.y
           + b2f_lo(v.w) * a1.z + b2f_hi(v.w) * a1.w;
    }
  }
  dot += __shfl_xor(dot, 1);
  if (half == 0 && gr < NN) alar[gr * 16 + blockIdx.x] = dot;
}

// ---------------- layer-2 GEMM: [MPAD x 1024] x [64 x 1024]^T -> fp32 [NN][64] ----------------
__global__ __launch_bounds__(256) void gemm2_64(const short* __restrict__ h1b,
                                                const short* __restrict__ Wt2,
                                                float* __restrict__ xlr2) {
  __shared__ short As[4][64][8];
  __shared__ short Bs[4][64][8];
  const int t = threadIdx.x;
  const int lane = t & 63;
  const int wv = t >> 6;
  const int wr = wv >> 1, wc = wv & 1;
  const int row0 = blockIdx.y * 64;
  const int r_st = t & 63;
  const int kc2 = t >> 6;
  f32x4 acc[2][2] = {};
  for (int k0 = 0; k0 < 1024; k0 += 32) {
    bf16x8 va = *(const bf16x8*)(h1b + (size_t)(row0 + r_st) * 1024 + k0 + kc2 * 8);
    bf16x8 vb = *(const bf16x8*)(Wt2 + (size_t)r_st * 1024 + k0 + kc2 * 8);
    __syncthreads();
    *(bf16x8*)&As[kc2][r_st][0] = va;
    *(bf16x8*)&Bs[kc2][r_st][0] = vb;
    __syncthreads();
    const int ks = lane >> 4;
    bf16x8 af0 = *(const bf16x8*)&As[ks][wr * 32 + (lane & 15)][0];
    bf16x8 af1 = *(const bf16x8*)&As[ks][wr * 32 + 16 + (lane & 15)][0];
    bf16x8 bf0 = *(const bf16x8*)&Bs[ks][wc * 32 + (lane & 15)][0];
    bf16x8 bf1 = *(const bf16x8*)&Bs[ks][wc * 32 + 16 + (lane & 15)][0];
    acc[0][0] = __builtin_amdgcn_mfma_f32_16x16x32_bf16(af0, bf0, acc[0][0], 0, 0, 0);
    acc[0][1] = __builtin_amdgcn_mfma_f32_16x16x32_bf16(af0, bf1, acc[0][1], 0, 0, 0);
    acc[1][0] = __builtin_amdgcn_mfma_f32_16x16x32_bf16(af1, bf0, acc[1][0], 0, 0, 0);
    acc[1][1] = __builtin_amdgcn_mfma_f32_16x16x32_bf16(af1, bf1, acc[1][1], 0, 0, 0);
  }
#pragma unroll
  for (int i = 0; i < 2; i++) {
#pragma unroll
    for (int reg = 0; reg < 4; reg++) {
      int gr = row0 + wr * 32 + i * 16 + (lane >> 4) * 4 + reg;
      if (gr < NN) {
#pragma unroll
        for (int j = 0; j < 2; j++) {
          int gc = wc * 32 + j * 16 + (lane & 15);
          xlr2[(size_t)gr * 64 + gc] = acc[i][j][reg];
        }
      }
    }
  }
}

// ---------------- fused layer-1: score + ONLINE softmax + agg + bias + ELU ----------------
// 2 waves per dst, lane owns 8 channels as named scalars. Depth-2 clamped-index
// software pipeline: edge j+2's csr_s/xl/alar loads issue while edge j computes.
__global__ __launch_bounds__(256) void fused1(const int* __restrict__ rowptr, const int* __restrict__ csr_s,
                                              const short* __restrict__ xlr, const float* __restrict__ att,
                                              const float* __restrict__ alar,
                                              const float* __restrict__ b1, short* __restrict__ h1b) {
  const int widx = threadIdx.x >> 6;
  const int lane = threadIdx.x & 63;
  const int d = blockIdx.x * 2 + (widx >> 1);
  const int ch = (widx & 1) * 512 + lane * 8;   // 8 channels; lanes 0-15 = one head
  const int h = ch >> 7;
  const uint4 rv = *(const uint4*)(xlr + (size_t)d * 2048 + 1024 + ch);
  const float xr0 = b2f_lo(rv.x), xr1 = b2f_hi(rv.x);
  const float xr2 = b2f_lo(rv.y), xr3 = b2f_hi(rv.y);
  const float xr4 = b2f_lo(rv.z), xr5 = b2f_hi(rv.z);
  const float xr6 = b2f_lo(rv.w), xr7 = b2f_hi(rv.w);
  const float4 ta = *(const float4*)(att + ch);
  const float4 tb = *(const float4*)(att + ch + 4);
  const float ar_h = alar[d * 16 + 8 + h];
  const int jb = rowptr[d], je = rowptr[d + 1];
  float m = -3.4e38f, den = 0.f;
  float c0 = 0.f, c1 = 0.f, c2 = 0.f, c3 = 0.f, c4 = 0.f, c5 = 0.f, c6 = 0.f, c7 = 0.f;
  if (jb < je) {
    const int jlast = je - 1;
    int s0 = csr_s[jb];
    uint4 v0 = *(const uint4*)(xlr + (size_t)s0 * 2048 + ch);
    float al0 = alar[s0 * 16 + h];
    int s1 = csr_s[min(jb + 1, jlast)];
    uint4 v1 = *(const uint4*)(xlr + (size_t)s1 * 2048 + ch);
    float al1 = alar[s1 * 16 + h];
    for (int j = jb; j < je; j++) {
      const uint4 v = v0;
      const float al_s = al0;
      v0 = v1; al0 = al1;
      const int sn = csr_s[min(j + 2, jlast)];
      v1 = *(const uint4*)(xlr + (size_t)sn * 2048 + ch);
      al1 = alar[sn * 16 + h];
      const float x0 = b2f_lo(v.x), x1 = b2f_hi(v.x);
      const float x2 = b2f_lo(v.y), x3 = b2f_hi(v.y);
      const float x4 = b2f_lo(v.z), x5 = b2f_hi(v.z);
      const float x6 = b2f_lo(v.w), x7 = b2f_hi(v.w);
      float p = fabsf(x0 + xr0) * ta.x;
      p += fabsf(x1 + xr1) * ta.y;
      p += fabsf(x2 + xr2) * ta.z;
      p += fabsf(x3 + xr3) * ta.w;
      p += fabsf(x4 + xr4) * tb.x;
      p += fabsf(x5 + xr5) * tb.y;
      p += fabsf(x6 + xr6) * tb.z;
      p += fabsf(x7 + xr7) * tb.w;
      p += __shfl_xor(p, 1);
      p += __shfl_xor(p, 2);
      p += __shfl_xor(p, 4);
      p += __shfl_xor(p, 8);      // sum over the 16 lanes of this head
      const float e = 0.4f * p + 0.6f * (al_s + ar_h);
      if (e > m) {                 // uniform across the 16-lane head group
        const float r = __expf(m - e);   // 0 on first edge
        c0 *= r; c1 *= r; c2 *= r; c3 *= r;
        c4 *= r; c5 *= r; c6 *= r; c7 *= r;
        den *= r;
        m = e;
      }
      const float w = __expf(e - m);
      den += w;
      c0 += w * x0; c1 += w * x1; c2 += w * x2; c3 += w * x3;
      c4 += w * x4; c5 += w * x5; c6 += w * x6; c7 += w * x7;
    }
  }
  const float inv = 1.f / (den + 1e-16f);
  const float4 b0 = *(const float4*)(b1 + ch);
  const float4 b4 = *(const float4*)(b1 + ch + 4);
  c0 = c0 * inv + b0.x; c1 = c1 * inv + b0.y; c2 = c2 * inv + b0.z; c3 = c3 * inv + b0.w;
  c4 = c4 * inv + b4.x; c5 = c5 * inv + b4.y; c6 = c6 * inv + b4.z; c7 = c7 * inv + b4.w;
  c0 = c0 > 0.f ? c0 : expm1f(c0);
  c1 = c1 > 0.f ? c1 : expm1f(c1);
  c2 = c2 > 0.f ? c2 : expm1f(c2);
  c3 = c3 > 0.f ? c3 : expm1f(c3);
  c4 = c4 > 0.f ? c4 : expm1f(c4);
  c5 = c5 > 0.f ? c5 : expm1f(c5);
  c6 = c6 > 0.f ? c6 : expm1f(c6);
  c7 = c7 > 0.f ? c7 : expm1f(c7);
  uint4 o;
  o.x = (unsigned)f2b(c0) | ((unsigned)f2b(c1) << 16);
  o.y = (unsigned)f2b(c2) | ((unsigned)f2b(c3) << 16);
  o.z = (unsigned)f2b(c4) | ((unsigned)f2b(c5) << 16);
  o.w = (unsigned)f2b(c6) | ((unsigned)f2b(c7) << 16);
  *(uint4*)(h1b + (size_t)d * 1024 + ch) = o;
}

// ---------------- fused layer-2: score + ONLINE softmax + agg + bias + log_softmax ----------------
// 32-lane group per dst; depth-2 clamped-index pipeline on the xlr2 gather.
__global__ __launch_bounds__(256) void fused2(const int* __restrict__ rowptr, const int* __restrict__ csr_s,
                                              const float* __restrict__ xlr2, const float* __restrict__ att2,
                                              const float* __restrict__ b2, float* __restrict__ out) {
  const int t = threadIdx.x;
  const int d = blockIdx.x * 8 + (t >> 5);
  const int c = t & 31;
  if (d >= NN) return;
  const float xr = xlr2[d * 64 + 32 + c];
  const float a2 = att2[c];
  const int jb = rowptr[d], je = rowptr[d + 1];
  float m = -3.4e38f, den = 0.f, acc = 0.f;
  if (jb < je) {
    const int jlast = je - 1;
    int s0 = csr_s[jb];
    float v0 = xlr2[s0 * 64 + c];
    int s1 = csr_s[min(jb + 1, jlast)];
    float v1 = xlr2[s1 * 64 + c];
    for (int j = jb; j < je; j++) {
      const float xv = v0;
      v0 = v1;
      const int sn = csr_s[min(j + 2, jlast)];
      v1 = xlr2[sn * 64 + c];
      float p = a2 * lrelu(xv + xr);
#pragma unroll
      for (int off = 16; off > 0; off >>= 1) p += __shfl_xor(p, off);
      if (p > m) {
        const float r = __expf(m - p);
        acc *= r; den *= r; m = p;
      }
      const float w = __expf(p - m);
      den += w;
      acc += w * xv;
    }
  }
  float v = acc / (den + 1e-16f) + b2[c];
  float mx = v;
#pragma unroll
  for (int off = 16; off > 0; off >>= 1) mx = fmaxf(mx, __shfl_xor(mx, off));
  float ex = __expf(v - mx);
  float sum = ex;
#pragma unroll
  for (int off = 16; off > 0; off >>= 1) sum += __shfl_xor(sum, off);
  out[d * 32 + c] = v - mx - logf(sum);
}

extern "C" void kernel_launch(void* const* d_in, const int* in_sizes, int n_in,
                              void* d_out, int out_size, void* d_ws, size_t ws_size,
                              hipStream_t stream) {
  const float* x    = (const float*)d_in[0];
  const int*   ei   = (const int*)d_in[1];
  const float* W1l  = (const float*)d_in[2];
  const float* W1r  = (const float*)d_in[3];
  const float* att1 = (const float*)d_in[4];
  const float* b1   = (const float*)d_in[5];
  const float* W2l  = (const float*)d_in[6];
  const float* W2r  = (const float*)d_in[7];
  const float* att2 = (const float*)d_in[8];
  const float* b2   = (const float*)d_in[9];
  float* out = (float*)d_out;

  // workspace layout
  short* Xb   = (short*)d_ws;                        // MPAD*256
  short* Wt1  = Xb + (size_t)MPAD * 256;             // 2048*256
  short* Wt2  = Wt1 + (size_t)2048 * 256;            // 64*1024
  short* xlr  = Wt2 + (size_t)64 * 1024;             // NN*2048 bf16 (xl | xr)
  short* h1b  = xlr + (size_t)NN * 2048;             // MPAD*1024 bf16
  float* xlr2 = (float*)(h1b + (size_t)MPAD * 1024); // NN*64
  float* alar = xlr2 + (size_t)NN * 64;              // NN*16
  int* deg    = (int*)(alar + (size_t)NN * 16);      // NN
  int* rowptr = deg + NN;                            // NN+1
  int* cursor = rowptr + NN + 1;                     // NN
  int* csr_s  = cursor + NN;                         // NE

  const int* src = ei;
  const int* dst = ei + NE;

  // CSR build + conversions (fused prep)
  hipMemsetAsync(deg, 0, NN * sizeof(int), stream);
  prep<<<NB_CVT + NB_W1 + NB_W2 + NB_DEG, 256, 0, stream>>>(x, Xb, W1l, W1r, Wt1,
                                                            W2l, W2r, Wt2, dst, deg);
  scan_rowptr<<<1, 1024, 0, stream>>>(deg, rowptr, cursor);
  csr_fill<<<(NE + 255) / 256, 256, 0, stream>>>(src, dst, cursor, csr_s);

  // layer-1 GEMM -> xlr bf16 [NN][2048] + alar (fused)
  {
    dim3 g(16, 79);
    gemm1_fused<<<g, 256, 0, stream>>>(Xb, Wt1, att1, xlr, alar);
  }

  // fused layer-1 attention (single pass over edges, 2 waves per dst)
  fused1<<<NN / 2, 256, 0, stream>>>(rowptr, csr_s, xlr, att1, alar, b1, h1b);

  // layer-2 GEMM -> xlr2 fp32 [NN][64]
  {
    dim3 g(1, MPAD / 64);
    gemm2_64<<<g, 256, 0, stream>>>(h1b, Wt2, xlr2);
  }

  // fused layer-2 attention + log_softmax
  fused2<<<(NN + 7) / 8, 256, 0, stream>>>(rowptr, csr_s, xlr2, att2, b2, out);
}